// Round 7
// baseline (295.327 us; speedup 1.0000x reference)
//
#include <hip/hip_runtime.h>
#include <math.h>

// Problem constants
#define Bn 4
#define Cn 64
#define Np 4096   // 64*64
#define NSPLIT 8
// SCALE * log2(e): folded into all Q pre-scales; attention uses exp2f (native v_exp_f32)
#define SCALE2 0.18033688011112042f

typedef unsigned short ushort_t;
typedef __attribute__((ext_vector_type(4))) float f32x4;
typedef __attribute__((ext_vector_type(8))) short bf16x8;
typedef __attribute__((ext_vector_type(4))) short bf16x4;

__device__ __forceinline__ float gelu_exact(float x) {
    return 0.5f * x * (1.0f + erff(x * 0.70710678118654752440f));
}
__device__ __forceinline__ ushort_t f2bf(float f) {       // RNE float->bf16
    unsigned int u = __float_as_uint(f);
    u += 0x7fffu + ((u >> 16) & 1u);
    return (ushort_t)(u >> 16);
}
__device__ __forceinline__ ushort_t f2bf_tr(float f) {    // truncating (1 VALU)
    return (ushort_t)(__float_as_uint(f) >> 16);
}
__device__ __forceinline__ float bf2f(ushort_t h) {
    return __uint_as_float(((unsigned int)h) << 16);
}
__device__ __forceinline__ void gload_lds16(const ushort_t* g, ushort_t* l) {
    __builtin_amdgcn_global_load_lds(
        (const __attribute__((address_space(1))) void*)g,
        (__attribute__((address_space(3))) void*)l, 16, 0, 0);
}
__device__ __forceinline__ bf16x8 cvt8(const float v[8]) {
    bf16x8 r;
    #pragma unroll
    for (int j = 0; j < 8; ++j) r[j] = (short)f2bf(v[j]);
    return r;
}
// bf16 pre-converted weights. Normal orientation: D[n][o].
__device__ __forceinline__ void gemm16b(const bf16x8 af[2], const ushort_t* __restrict__ Wb,
                                        int l16, int quad, f32x4* acc) {
    #pragma unroll
    for (int cb = 0; cb < 4; ++cb) {
        #pragma unroll
        for (int ks = 0; ks < 2; ++ks) {
            bf16x8 bw = *(const bf16x8*)(Wb + (cb * 16 + l16) * 64 + ks * 32 + quad * 8);
            acc[cb] = __builtin_amdgcn_mfma_f32_16x16x32_bf16(af[ks], bw, acc[cb], 0, 0, 0);
        }
    }
}
// Transposed orientation: D[o][n] -> ushort4 channel-packed stores.
__device__ __forceinline__ void gemm16Tb(const bf16x8 af[2], const ushort_t* __restrict__ Wb,
                                         int l16, int quad, f32x4* acc) {
    #pragma unroll
    for (int cb = 0; cb < 4; ++cb) {
        #pragma unroll
        for (int ks = 0; ks < 2; ++ks) {
            bf16x8 bw = *(const bf16x8*)(Wb + (cb * 16 + l16) * 64 + ks * 32 + quad * 8);
            acc[cb] = __builtin_amdgcn_mfma_f32_16x16x32_bf16(bw, af[ks], acc[cb], 0, 0, 0);
        }
    }
}
__device__ __forceinline__ void aload(const float* xs, int row, int quad, bf16x8 af[2]) {
    #pragma unroll
    for (int ks = 0; ks < 2; ++ks) {
        float v[8];
        #pragma unroll
        for (int j = 0; j < 8; ++j) v[j] = xs[(ks * 32 + quad * 8 + j) * 65 + row];
        af[ks] = cvt8(v);
    }
}
__device__ __forceinline__ void stage_bchw(const float* __restrict__ X, int b, int n0, int t,
                                           float* xs) {
    #pragma unroll
    for (int u = 0; u < 16; ++u) {
        int idx = t + u * 256;
        int c = idx >> 6, nl = idx & 63;
        xs[c * 65 + nl] = X[((size_t)(b * Cn + c)) * Np + n0 + nl];
    }
}
// combine NSPLIT bf16 attention partials * 1/l -> fp32 xs tile (vectorized ushort4 loads)
__device__ __forceinline__ void stage_comb(const ushort_t* __restrict__ OpB, const float* linv,
                                           int b, int n0, int t, float* xs) {
    const size_t SS = (size_t)Bn * Np * Cn;
    int c4 = (t & 15) * 4;
    #pragma unroll
    for (int u = 0; u < 4; ++u) {
        int nl = (t >> 4) + u * 16;
        size_t gi = ((size_t)(b * Np + n0 + nl)) * Cn + c4;
        float s0 = 0.f, s1 = 0.f, s2 = 0.f, s3 = 0.f;
        #pragma unroll
        for (int sp = 0; sp < NSPLIT; ++sp) {
            ushort4 a = *(const ushort4*)(OpB + (size_t)sp * SS + gi);
            s0 += bf2f(a.x); s1 += bf2f(a.y); s2 += bf2f(a.z); s3 += bf2f(a.w);
        }
        float li = linv[nl];
        xs[(c4 + 0) * 65 + nl] = s0 * li;
        xs[(c4 + 1) * 65 + nl] = s1 * li;
        xs[(c4 + 2) * 65 + nl] = s2 * li;
        xs[(c4 + 3) * 65 + nl] = s3 * li;
    }
}
__device__ __forceinline__ void store_bnc_T(ushort_t* __restrict__ Y, int b, int n, int quad,
                                            const f32x4* acc, const float* __restrict__ bias,
                                            float mult) {
    #pragma unroll
    for (int cb = 0; cb < 4; ++cb) {
        int o0 = cb * 16 + quad * 4;
        ushort4 pk;
        pk.x = f2bf((acc[cb][0] + bias[o0 + 0]) * mult);
        pk.y = f2bf((acc[cb][1] + bias[o0 + 1]) * mult);
        pk.z = f2bf((acc[cb][2] + bias[o0 + 2]) * mult);
        pk.w = f2bf((acc[cb][3] + bias[o0 + 3]) * mult);
        *(ushort4*)(Y + ((size_t)(b * Np + n)) * Cn + o0) = pk;
    }
}
__device__ __forceinline__ void store_bchw_bf16(ushort_t* __restrict__ Y, int b, int nb, int l16,
                                                const f32x4* acc, const float* __restrict__ bias) {
    #pragma unroll
    for (int cb = 0; cb < 4; ++cb) {
        int col = cb * 16 + l16;
        float bb = bias[col];
        ushort4 pk;
        pk.x = f2bf(acc[cb][0] + bb); pk.y = f2bf(acc[cb][1] + bb);
        pk.z = f2bf(acc[cb][2] + bb); pk.w = f2bf(acc[cb][3] + bb);
        *(ushort4*)(Y + ((size_t)(b * Cn + col)) * Np + nb) = pk;
    }
}

// ---------------------------------------------------------------- avgpool 2x2 + GAP partials + wcomb + weight bf16 pre-convert
__global__ void avgpool_kernel(const float* __restrict__ x, float* __restrict__ xp,
                               float* __restrict__ gap4k,
                               const float* __restrict__ convh_w, const float* __restrict__ convh_b,
                               const float* __restrict__ sch_pw, const float* __restrict__ sch_pwb,
                               const float* __restrict__ scv_pw, const float* __restrict__ scv_pwb,
                               ushort_t* __restrict__ Wc1b, ushort_t* __restrict__ Wc2b,
                               float* __restrict__ bcv,
                               const float* __restrict__ Wq, const float* __restrict__ Wk,
                               const float* __restrict__ Wv, const float* __restrict__ Wo,
                               const float* __restrict__ Wl, const float* __restrict__ Wp,
                               const float* __restrict__ dscpw, ushort_t* __restrict__ Wball) {
    if (blockIdx.x < 4096) {
        int idx = blockIdx.x * 256 + threadIdx.x;
        int j  = idx & 63;
        int i  = (idx >> 6) & 63;
        int bc = idx >> 12;
        const float* p = x + ((size_t)bc * 128 + 2 * i) * 128 + 2 * j;
        float v = 0.25f * (p[0] + p[1] + p[128] + p[129]);
        xp[idx] = v;
        float s = v;
        #pragma unroll
        for (int off = 1; off < 64; off <<= 1) s += __shfl_xor(s, off, 64);
        __shared__ float sm[4];
        if ((threadIdx.x & 63) == 0) sm[threadIdx.x >> 6] = s;
        __syncthreads();
        if (threadIdx.x == 0) gap4k[blockIdx.x] = sm[0] + sm[1] + sm[2] + sm[3];
    } else if (blockIdx.x < 4128) {
        int g = (blockIdx.x - 4096) * 256 + threadIdx.x;   // 8192 threads
        int sel = g >> 12, idx = g & 4095;
        int o = idx >> 6, c = idx & 63;
        const float* pw = sel ? scv_pw : sch_pw;
        float acc = 0.f;
        #pragma unroll 8
        for (int m = 0; m < 64; ++m) acc += convh_w[o * 64 + m] * pw[m * 64 + c];
        (sel ? Wc2b : Wc1b)[idx] = f2bf(acc * SCALE2);
        if (g < 64) {
            float ab = convh_b[g];
            for (int m = 0; m < 64; ++m) ab += convh_w[g * 64 + m] * (sch_pwb[m] + scv_pwb[m]);
            bcv[g] = ab * SCALE2;
        }
    } else {
        // pre-convert 7 weight matrices (4096 each) to bf16: Wq,Wk,Wv,Wo,Wl,Wp,dsc_pw
        int g = (blockIdx.x - 4128) * 256 + threadIdx.x;   // 28672 threads
        int which = g >> 12, idx = g & 4095;
        const float* srcs[7] = {Wq, Wk, Wv, Wo, Wl, Wp, dscpw};
        Wball[g] = f2bf(srcs[which][idx]);
    }
}

// ---------------------------------------------------------------- merged: QKV+Wo (x<64) | dwpair (x>=64)
__global__ __launch_bounds__(256) void qkv_dw_kernel(
    const float* __restrict__ xp, const float* __restrict__ gap4k,
    const ushort_t* __restrict__ Wqb, const float* __restrict__ bq,
    const ushort_t* __restrict__ Wkb, const float* __restrict__ bk,
    const ushort_t* __restrict__ Wvb, const float* __restrict__ bv,
    const ushort_t* __restrict__ Wob, const float* __restrict__ bo,
    ushort_t* __restrict__ qb, ushort_t* __restrict__ kb, ushort_t* __restrict__ vb,
    float* __restrict__ xV, ushort_t* __restrict__ xVtb,
    const float* __restrict__ wv5, const float* __restrict__ bv5,
    const float* __restrict__ wh5, const float* __restrict__ bh5,
    ushort_t* __restrict__ gh, ushort_t* __restrict__ gv) {
    int b = blockIdx.y, t = threadIdx.x;
    if (blockIdx.x >= 64) {
        // ---- dwpair: 4 consecutive elems/thread, float4 loads, bf16 outputs
        int part = blockIdx.x - 64;                  // 0..255
        int e = part * 1024 + t * 4;                 // within-batch offset
        size_t base = (size_t)b * (Cn * Np) + e;
        int c = e >> 12, i = (e >> 6) & 63, j = e & 63;
        const float* p = xp + ((size_t)(b * Cn + c)) * Np;
        float accV[4], accH[4];
        #pragma unroll
        for (int k = 0; k < 4; ++k) { accV[k] = bv5[c]; accH[k] = bh5[c]; }
        // vertical 5-tap: rows i-2..i+2, cols j..j+3 (float4)
        #pragma unroll
        for (int d = 0; d < 5; ++d) {
            int ii = i + d - 2;
            if (ii >= 0 && ii < 64) {
                f32x4 r = *(const f32x4*)(p + ii * 64 + j);
                float w = wv5[c * 5 + d];
                accV[0] += w * r[0]; accV[1] += w * r[1];
                accV[2] += w * r[2]; accV[3] += w * r[3];
            }
        }
        // horizontal 5-tap: row i, cols j-2..j+5
        f32x4 c0 = *(const f32x4*)(p + i * 64 + j);
        float col[8];
        col[2] = c0[0]; col[3] = c0[1]; col[4] = c0[2]; col[5] = c0[3];
        col[0] = (j >= 2)     ? p[i * 64 + j - 2] : 0.f;
        col[1] = (j >= 1)     ? p[i * 64 + j - 1] : 0.f;
        col[6] = (j + 4 < 64) ? p[i * 64 + j + 4] : 0.f;
        col[7] = (j + 5 < 64) ? p[i * 64 + j + 5] : 0.f;
        #pragma unroll
        for (int k = 0; k < 4; ++k) {
            #pragma unroll
            for (int d = 0; d < 5; ++d) accH[k] += wh5[c * 5 + d] * col[k + d];
        }
        ushort4 ph, pv_;
        ph.x = f2bf(gelu_exact(accV[0])); ph.y = f2bf(gelu_exact(accV[1]));
        ph.z = f2bf(gelu_exact(accV[2])); ph.w = f2bf(gelu_exact(accV[3]));
        pv_.x = f2bf(gelu_exact(accH[0])); pv_.y = f2bf(gelu_exact(accH[1]));
        pv_.z = f2bf(gelu_exact(accH[2])); pv_.w = f2bf(gelu_exact(accH[3]));
        *(ushort4*)(gh + base) = ph;
        *(ushort4*)(gv + base) = pv_;
        return;
    }
    // ---- QKV + Wo
    __shared__ float xs[64 * 65];
    __shared__ float gl[64];
    int n0 = blockIdx.x * 64;
    int wv_ = t >> 6, lane = t & 63, l16 = lane & 15, quad = lane >> 4;
    stage_bchw(xp, b, n0, t, xs);
    if (t < 64) {
        float s = 0.f;
        #pragma unroll
        for (int u = 0; u < 16; ++u) s += gap4k[(b * 64 + t) * 16 + u];
        gl[t] = s * (1.f / 4096.f);
    }
    __syncthreads();
    int row = wv_ * 16 + l16;
    int n   = n0 + wv_ * 16 + l16;
    int nb  = n0 + wv_ * 16 + quad * 4;
    bf16x8 ar[2], ag[2];
    #pragma unroll
    for (int ks = 0; ks < 2; ++ks) {
        float vr[8], vg[8];
        #pragma unroll
        for (int j = 0; j < 8; ++j) {
            int k = ks * 32 + quad * 8 + j;
            float xv = xs[k * 65 + row];
            vr[j] = xv; vg[j] = xv * gl[k];
        }
        ar[ks] = cvt8(vr); ag[ks] = cvt8(vg);
    }
    f32x4 acc[4];
    #pragma unroll
    for (int cb = 0; cb < 4; ++cb) acc[cb] = (f32x4){0.f, 0.f, 0.f, 0.f};
    gemm16Tb(ag, Wqb, l16, quad, acc);
    store_bnc_T(qb, b, n, quad, acc, bq, SCALE2);
    #pragma unroll
    for (int cb = 0; cb < 4; ++cb) acc[cb] = (f32x4){0.f, 0.f, 0.f, 0.f};
    gemm16Tb(ag, Wkb, l16, quad, acc);
    store_bnc_T(kb, b, n, quad, acc, bk, 1.f);
    #pragma unroll
    for (int cb = 0; cb < 4; ++cb) acc[cb] = (f32x4){0.f, 0.f, 0.f, 0.f};
    gemm16b(ag, Wvb, l16, quad, acc);
    store_bchw_bf16(vb, b, nb, l16, acc, bv);
    #pragma unroll
    for (int cb = 0; cb < 4; ++cb) acc[cb] = (f32x4){0.f, 0.f, 0.f, 0.f};
    gemm16b(ar, Wob, l16, quad, acc);
    #pragma unroll
    for (int cb = 0; cb < 4; ++cb) {
        int col = cb * 16 + l16;
        float bb = bo[col];
        ushort4 pk;
        float y0 = acc[cb][0] + bb, y1 = acc[cb][1] + bb, y2 = acc[cb][2] + bb, y3 = acc[cb][3] + bb;
        xV[((size_t)(b * Np + nb + 0)) * Cn + col] = y0;
        xV[((size_t)(b * Np + nb + 1)) * Cn + col] = y1;
        xV[((size_t)(b * Np + nb + 2)) * Cn + col] = y2;
        xV[((size_t)(b * Np + nb + 3)) * Cn + col] = y3;
        pk.x = f2bf(y0); pk.y = f2bf(y1); pk.z = f2bf(y2); pk.w = f2bf(y3);
        *(ushort4*)(xVtb + ((size_t)(b * Cn + col)) * Np + nb) = pk;
    }
}

// ---------------------------------------------------------------- attention body (device)
// WAVE-PRIVATE LDS attention with REGISTER double-buffering: 3 LDS buffers/wave,
// per iteration: stage(t+2) -> vmcnt(4) -> ds_read tile t+1 into REGISTERS ->
// compute tile t from registers (pure reg MFMA/VALU). The ds_read latency of
// tile t+1 hides under compute of tile t; the asm vmcnt only orders
// gload_lds -> ds_read (required anyway). Buffer t%3 is overwritten at t+2,
// one full iteration after its reads retired (race-free). No barriers anywhere.
// K tile [16][64ch], 16B-chunk XOR swizzle key=row&7. V^T tile [64ch][16kv] with
// 2-chunk XOR swizzle key=(row>>2)&1, both applied via pre-swizzled global source.
__device__ __forceinline__ void attn_wave(
    int wid, int b, const ushort_t* __restrict__ Qb, const ushort_t* __restrict__ Kb,
    const ushort_t* __restrict__ Vtb, ushort_t* __restrict__ OpB, float* __restrict__ Lpart,
    ushort_t* lds /* per-wave 6144 ushorts = 3 buffers x (1024 K + 1024 V) */) {
    int split = wid >> 7;            // 0..7
    int qt    = wid & 127;           // 0..127
    int n0    = qt * 32;
    int lane  = threadIdx.x & 63;
    int l16   = lane & 15, quad = lane >> 4;
    int kvbase = split * (Np / NSPLIT);      // 512 kv per split

    const ushort_t* qp = Qb + ((size_t)(b * Np) + n0 + l16) * Cn + quad * 8;
    bf16x8 aq00 = *(const bf16x8*)(qp);
    bf16x8 aq01 = *(const bf16x8*)(qp + 32);
    bf16x8 aq10 = *(const bf16x8*)(qp + 16 * Cn);
    bf16x8 aq11 = *(const bf16x8*)(qp + 16 * Cn + 32);
    asm volatile("s_waitcnt vmcnt(0)" ::: "memory");   // retire Q loads: vmcnt now counts only staging

    f32x4 oa0[4], oa1[4];
    float psum0 = 0.f, psum1 = 0.f;
    #pragma unroll
    for (int db = 0; db < 4; ++db) {
        oa0[db] = (f32x4){0.f, 0.f, 0.f, 0.f};
        oa1[db] = (f32x4){0.f, 0.f, 0.f, 0.f};
    }

    // staging bases (per-lane global; advance per tile).
    // K: row lane>>3 (+8 for inst 1), source chunk pre-swizzled (lane&7)^(lane>>3).
    // V: row lane>>1 (+32 for inst 1), source chunk (lane&1)^((lane>>3)&1)
    const ushort_t* gK = Kb + ((size_t)b * Np + kvbase + (lane >> 3)) * Cn
                            + (((lane & 7) ^ (lane >> 3)) * 8);
    const ushort_t* gV = Vtb + ((size_t)(b * Cn) + (lane >> 1)) * Np + kvbase
                             + (((lane & 1) ^ ((lane >> 3) & 1)) * 8);

    // loop-invariant LDS read pointers (buffer offset added per call)
    const ushort_t* kr0 = lds + l16 * 64 + ((quad      ^ (l16 & 7))) * 8;
    const ushort_t* kr1 = lds + l16 * 64 + (((quad + 4) ^ (l16 & 7))) * 8;
    const ushort_t* vrb = lds + 1024 + l16 * 16
                        + (((quad >> 1) ^ ((l16 >> 2) & 1)) * 8) + (quad & 1) * 4;

    auto stage = [&](int buf3) {
        ushort_t* kd = lds + buf3 * 2048;
        gload_lds16(gK,       kd);         // K rows 0-7 of tile
        gload_lds16(gK + 512, kd + 512);   // K rows 8-15
        ushort_t* vd = kd + 1024;
        gload_lds16(gV,                   vd);         // V rows 0-31
        gload_lds16(gV + (size_t)32 * Np, vd + 512);   // V rows 32-63
        gK += 16 * Cn;    // next 16-kv tile
        gV += 16;
    };

    auto ldread = [&](int bo, bf16x8* kf, bf16x4* vf) {
        kf[0] = *(const bf16x8*)(kr0 + bo);
        kf[1] = *(const bf16x8*)(kr1 + bo);
        #pragma unroll
        for (int db = 0; db < 4; ++db) vf[db] = *(const bf16x4*)(vrb + bo + db * 256);
    };

    auto computeR = [&](const bf16x8* kf, const bf16x4* vf) {
        f32x4 sa0 = (f32x4){0.f, 0.f, 0.f, 0.f};
        f32x4 sa1 = (f32x4){0.f, 0.f, 0.f, 0.f};
        __builtin_amdgcn_s_setprio(1);
        sa0 = __builtin_amdgcn_mfma_f32_16x16x32_bf16(kf[0], aq00, sa0, 0, 0, 0);
        sa0 = __builtin_amdgcn_mfma_f32_16x16x32_bf16(kf[1], aq01, sa0, 0, 0, 0);
        sa1 = __builtin_amdgcn_mfma_f32_16x16x32_bf16(kf[0], aq10, sa1, 0, 0, 0);
        sa1 = __builtin_amdgcn_mfma_f32_16x16x32_bf16(kf[1], aq11, sa1, 0, 0, 0);
        __builtin_amdgcn_s_setprio(0);
        float p0 = exp2f(sa0[0]), p1 = exp2f(sa0[1]), p2 = exp2f(sa0[2]), p3 = exp2f(sa0[3]);
        psum0 += (p0 + p1) + (p2 + p3);
        bf16x4 pb0;
        pb0[0] = (short)f2bf_tr(p0); pb0[1] = (short)f2bf_tr(p1);
        pb0[2] = (short)f2bf_tr(p2); pb0[3] = (short)f2bf_tr(p3);
        float q0 = exp2f(sa1[0]), q1 = exp2f(sa1[1]), q2 = exp2f(sa1[2]), q3 = exp2f(sa1[3]);
        psum1 += (q0 + q1) + (q2 + q3);
        bf16x4 pb1;
        pb1[0] = (short)f2bf_tr(q0); pb1[1] = (short)f2bf_tr(q1);
        pb1[2] = (short)f2bf_tr(q2); pb1[3] = (short)f2bf_tr(q3);
        __builtin_amdgcn_s_setprio(1);
        #pragma unroll
        for (int db = 0; db < 4; ++db) {
            oa0[db] = __builtin_amdgcn_mfma_f32_16x16x16bf16_1k(vf[db], pb0, oa0[db], 0, 0, 0);
            oa1[db] = __builtin_amdgcn_mfma_f32_16x16x16bf16_1k(vf[db], pb1, oa1[db], 0, 0, 0);
        }
        __builtin_amdgcn_s_setprio(0);
    };

    const int NT = (Np / NSPLIT) / 16;     // 32 tiles of 16 kv
    bf16x8 kfA[2], kfB[2];
    bf16x4 vfA[4], vfB[4];
    stage(0);                               // tile 0 -> buf0
    stage(1);                               // tile 1 -> buf1 (out = 8)
    asm volatile("s_waitcnt vmcnt(4)" ::: "memory");   // tile 0 staged
    ldread(0, kfA, vfA);                    // tile 0 -> regs A
    #pragma unroll 1
    for (int mm = 0; mm < NT - 1; ++mm) {
        int s = mm + 2;
        if (s < NT) {
            stage(s % 3);                   // overwrite buf of tile mm-1 (reads retired)
            asm volatile("s_waitcnt vmcnt(4)" ::: "memory");   // tile mm+1 staged
        } else {
            asm volatile("s_waitcnt vmcnt(0)" ::: "memory");
        }
        int bo = ((mm + 1) % 3) * 2048;
        if (mm & 1) {
            ldread(bo, kfA, vfA);           // tile mm+1 -> regs A
            computeR(kfB, vfB);             // compute tile mm from regs B
        } else {
            ldread(bo, kfB, vfB);           // tile mm+1 -> regs B
            computeR(kfA, vfA);             // compute tile mm from regs A
        }
    }
    if ((NT - 1) & 1) computeR(kfB, vfB); else computeR(kfA, vfA);

    psum0 += __shfl_xor(psum0, 16, 64);
    psum0 += __shfl_xor(psum0, 32, 64);
    psum1 += __shfl_xor(psum1, 16, 64);
    psum1 += __shfl_xor(psum1, 32, 64);
    size_t obase = ((size_t)(split * Bn + b)) * Np;
    int n = n0 + l16;
    if (quad == 0) {
        Lpart[obase + n]      = psum0;
        Lpart[obase + n + 16] = psum1;
    }
    #pragma unroll
    for (int db = 0; db < 4; ++db) {
        ushort4 pk;
        pk.x = f2bf(oa0[db][0]); pk.y = f2bf(oa0[db][1]);
        pk.z = f2bf(oa0[db][2]); pk.w = f2bf(oa0[db][3]);
        *(ushort4*)(OpB + (obase + n) * Cn + db * 16 + quad * 4) = pk;
        ushort4 qk;
        qk.x = f2bf(oa1[db][0]); qk.y = f2bf(oa1[db][1]);
        qk.z = f2bf(oa1[db][2]); qk.w = f2bf(oa1[db][3]);
        *(ushort4*)(OpB + (obase + n + 16) * Cn + db * 16 + quad * 4) = qk;
    }
}

// hpg body: bf16 gh/gv staged [n][c] stride 72, combined 1x1 (SCALE2 folded, bf16 weights) -> xQb
__device__ __forceinline__ void hpg_body(
    int tile, int b, const ushort_t* __restrict__ gh, const ushort_t* __restrict__ gv,
    const ushort_t* __restrict__ Wc1b, const ushort_t* __restrict__ Wc2b,
    const float* __restrict__ bcv,
    ushort_t* __restrict__ xQb, ushort_t* smem) {
    ushort_t* xs1 = smem;            // 64 x 72
    ushort_t* xs2 = smem + 4608;
    int n0 = tile * 64, t = threadIdx.x;
    int wv_ = t >> 6, lane = t & 63, l16 = lane & 15, quad = lane >> 4;
    #pragma unroll
    for (int u = 0; u < 4; ++u) {
        int lin = u * 256 + t;
        int c = lin >> 4, nl4 = (lin & 15) * 4;
        size_t gi = ((size_t)(b * Cn + c)) * Np + n0 + nl4;
        ushort4 g1 = *(const ushort4*)(gh + gi);
        ushort4 g2 = *(const ushort4*)(gv + gi);
        xs1[(nl4 + 0) * 72 + c] = g1.x; xs1[(nl4 + 1) * 72 + c] = g1.y;
        xs1[(nl4 + 2) * 72 + c] = g1.z; xs1[(nl4 + 3) * 72 + c] = g1.w;
        xs2[(nl4 + 0) * 72 + c] = g2.x; xs2[(nl4 + 1) * 72 + c] = g2.y;
        xs2[(nl4 + 2) * 72 + c] = g2.z; xs2[(nl4 + 3) * 72 + c] = g2.w;
    }
    __syncthreads();
    int row = wv_ * 16 + l16;
    bf16x8 a1[2], a2[2];
    #pragma unroll
    for (int ks = 0; ks < 2; ++ks) {
        a1[ks] = *(const bf16x8*)(xs1 + row * 72 + ks * 32 + quad * 8);
        a2[ks] = *(const bf16x8*)(xs2 + row * 72 + ks * 32 + quad * 8);
    }
    f32x4 acc[4];
    #pragma unroll
    for (int cb = 0; cb < 4; ++cb) acc[cb] = (f32x4){0.f, 0.f, 0.f, 0.f};
    gemm16Tb(a1, Wc1b, l16, quad, acc);
    gemm16Tb(a2, Wc2b, l16, quad, acc);
    store_bnc_T(xQb, b, n0 + wv_ * 16 + l16, quad, acc, bcv, 1.f);
}

// merged launch: x<256 -> attention (4 independent waves/block) ; x>=256 -> hpg tile (x-256)
__global__ __launch_bounds__(256) void attn_hpg_kernel(
    const ushort_t* __restrict__ Qb, const ushort_t* __restrict__ Kb,
    const ushort_t* __restrict__ Vtb, ushort_t* __restrict__ OpB, float* __restrict__ Lpart,
    const ushort_t* __restrict__ gh, const ushort_t* __restrict__ gv,
    const ushort_t* __restrict__ Wc1b, const ushort_t* __restrict__ Wc2b,
    const float* __restrict__ bcv, ushort_t* __restrict__ xQb) {
    __shared__ ushort_t smem[24576];   // attn: 4 waves x 6144; hpg: 9216 used
    int b = blockIdx.y;
    if (blockIdx.x < 256) {
        int wave = threadIdx.x >> 6;
        attn_wave(blockIdx.x * 4 + wave, b, Qb, Kb, Vtb, OpB, Lpart, smem + wave * 6144);
    } else {
        hpg_body(blockIdx.x - 256, b, gh, gv, Wc1b, Wc2b, bcv, xQb, smem);
    }
}

// ---------------------------------------------------------------- combine(attn1)+Wl -> xKb
__global__ __launch_bounds__(256) void wl_mfma(
    const ushort_t* __restrict__ OpB, const float* __restrict__ Lp,
    const ushort_t* __restrict__ Wlb, const float* __restrict__ bl, ushort_t* __restrict__ xKb) {
    __shared__ float xs[64 * 65];
    __shared__ float linv[64];
    int b = blockIdx.y, n0 = blockIdx.x * 64, t = threadIdx.x;
    int wv_ = t >> 6, lane = t & 63, l16 = lane & 15, quad = lane >> 4;
    if (t < 64) {
        size_t li = (size_t)b * Np + n0 + t;
        const size_t LS = (size_t)Bn * Np;
        float s = 0.f;
        #pragma unroll
        for (int sp = 0; sp < NSPLIT; ++sp) s += Lp[(size_t)sp * LS + li];
        linv[t] = 1.f / s;
    }
    __syncthreads();
    stage_comb(OpB, linv, b, n0, t, xs);
    __syncthreads();
    bf16x8 af[2];
    aload(xs, wv_ * 16 + l16, quad, af);
    f32x4 acc[4];
    #pragma unroll
    for (int cb = 0; cb < 4; ++cb) acc[cb] = (f32x4){0.f, 0.f, 0.f, 0.f};
    gemm16Tb(af, Wlb, l16, quad, acc);
    store_bnc_T(xKb, b, n0 + wv_ * 16 + l16, quad, acc, bl, 1.f);
}

// ---------------------------------------------------------------- combine(attn2)+Wp+res+LayerNorm -> BCHW
__global__ __launch_bounds__(256) void linln_mfma(
    const ushort_t* __restrict__ OpB, const float* __restrict__ Lp,
    const ushort_t* __restrict__ Wpb, const float* __restrict__ bp,
    const float* __restrict__ xV, const float* __restrict__ g, const float* __restrict__ beta,
    float* __restrict__ out) {
    __shared__ float xs[64 * 65];
    __shared__ float linv[64];
    int b = blockIdx.y, n0 = blockIdx.x * 64, t = threadIdx.x;
    int wv_ = t >> 6, lane = t & 63, l16 = lane & 15, quad = lane >> 4;
    if (t < 64) {
        size_t li = (size_t)b * Np + n0 + t;
        const size_t LS = (size_t)Bn * Np;
        float s = 0.f;
        #pragma unroll
        for (int sp = 0; sp < NSPLIT; ++sp) s += Lp[(size_t)sp * LS + li];
        linv[t] = 1.f / s;
    }
    __syncthreads();
    stage_comb(OpB, linv, b, n0, t, xs);
    __syncthreads();
    bf16x8 af[2];
    aload(xs, wv_ * 16 + l16, quad, af);
    f32x4 acc[4];
    #pragma unroll
    for (int cb = 0; cb < 4; ++cb) acc[cb] = (f32x4){0.f, 0.f, 0.f, 0.f};
    gemm16b(af, Wpb, l16, quad, acc);
    int nb = n0 + wv_ * 16 + quad * 4;
    float vals[4][4], gc[4], bec[4];
    #pragma unroll
    for (int cb = 0; cb < 4; ++cb) {
        int col = cb * 16 + l16;
        float bb = bp[col];
        gc[cb] = g[col]; bec[cb] = beta[col];
        #pragma unroll
        for (int r = 0; r < 4; ++r)
            vals[cb][r] = acc[cb][r] + bb + xV[((size_t)(b * Np + nb + r)) * Cn + col];
    }
    f32x4 yn[4];
    #pragma unroll
    for (int r = 0; r < 4; ++r) {
        float s = 0.f, s2 = 0.f;
        #pragma unroll
        for (int cb = 0; cb < 4; ++cb) { s += vals[cb][r]; s2 += vals[cb][r] * vals[cb][r]; }
        #pragma unroll
        for (int off = 1; off < 16; off <<= 1) {
            s  += __shfl_xor(s, off, 64);
            s2 += __shfl_xor(s2, off, 64);
        }
        float mu  = s * (1.f / 64.f);
        float var = s2 * (1.f / 64.f) - mu * mu;
        float ivs = rsqrtf(var + 1e-5f);
        #pragma unroll
        for (int cb = 0; cb < 4; ++cb)
            yn[cb][r] = (vals[cb][r] - mu) * ivs * gc[cb] + bec[cb];
    }
    #pragma unroll
    for (int cb = 0; cb < 4; ++cb)
        *(f32x4*)(out + ((size_t)(b * Cn + cb * 16 + l16)) * Np + nb) = yn[cb];
}

// ---------------------------------------------------------------- dw3x3 + GELU (elementwise, 1 elem/thread)
__global__ void dw3x3_gelu_kernel(const float* __restrict__ xin, const float* __restrict__ w,
                                  const float* __restrict__ bias, float* __restrict__ out) {
    int idx = blockIdx.x * 256 + threadIdx.x;
    int j = idx & 63, i = (idx >> 6) & 63, bc = idx >> 12, c = bc & 63;
    const float* p = xin + (size_t)bc * Np;
    float acc = bias[c];
    #pragma unroll
    for (int dy = 0; dy < 3; ++dy) {
        int ii = i + dy - 1;
        if (ii < 0 || ii >= 64) continue;
        #pragma unroll
        for (int dx = 0; dx < 3; ++dx) {
            int jj = j + dx - 1;
            if (jj < 0 || jj >= 64) continue;
            acc += w[c * 9 + dy * 3 + dx] * p[ii * 64 + jj];
        }
    }
    out[idx] = gelu_exact(acc);
}

// ---------------------------------------------------------------- dsc 1x1 (bf16 weights) + residual -> BCHW
__global__ __launch_bounds__(256) void dsc_mfma(
    const float* __restrict__ X, const ushort_t* __restrict__ Wb, const float* __restrict__ bias,
    const float* __restrict__ res, float* __restrict__ out) {
    __shared__ float xs[64 * 65];
    int b = blockIdx.y, n0 = blockIdx.x * 64, t = threadIdx.x;
    int wv_ = t >> 6, lane = t & 63, l16 = lane & 15, quad = lane >> 4;
    stage_bchw(X, b, n0, t, xs);
    __syncthreads();
    bf16x8 af[2];
    aload(xs, wv_ * 16 + l16, quad, af);
    f32x4 acc[4];
    #pragma unroll
    for (int cb = 0; cb < 4; ++cb) acc[cb] = (f32x4){0.f, 0.f, 0.f, 0.f};
    gemm16b(af, Wb, l16, quad, acc);
    int nb = n0 + wv_ * 16 + quad * 4;
    #pragma unroll
    for (int cb = 0; cb < 4; ++cb) {
        int col = cb * 16 + l16;
        float bb = bias[col];
        size_t oi = ((size_t)(b * Cn + col)) * Np + nb;
        f32x4 rv = *(const f32x4*)(res + oi);
        f32x4 v4;
        #pragma unroll
        for (int r = 0; r < 4; ++r) v4[r] = acc[cb][r] + bb + rv[r];
        *(f32x4*)(out + oi) = v4;
    }
}

// ---------------------------------------------------------------- bilinear x2 upsample (4 outs/thread)
__global__ void upsample_kernel(const float* __restrict__ in, float* __restrict__ out) {
    int idx = blockIdx.x * 256 + threadIdx.x;     // 1,048,576 threads
    int x4 = (idx & 31) * 4;
    int y  = (idx >> 5) & 127;
    int bc = idx >> 12;
    float sy = y * (63.f / 127.f);
    int y0 = (int)sy;
    float fy = sy - y0;
    int y1 = min(y0 + 1, 63);
    const float* p0 = in + (size_t)bc * Np + y0 * 64;
    const float* p1 = in + (size_t)bc * Np + y1 * 64;
    f32x4 o;
    #pragma unroll
    for (int k = 0; k < 4; ++k) {
        int xo = x4 + k;
        float sx = xo * (63.f / 127.f);
        int x0 = (int)sx;
        float fx = sx - x0;
        int x1 = min(x0 + 1, 63);
        float r0 = p0[x0] + (p0[x1] - p0[x0]) * fx;
        float r1 = p1[x0] + (p1[x1] - p1[x0]) * fx;
        o[k] = r0 + (r1 - r0) * fy;
    }
    *(f32x4*)(out + (size_t)idx * 4) = o;
}

// ----------------------------------------------------------------
extern "C" void kernel_launch(void* const* d_in, const int* in_sizes, int n_in,
                              void* d_out, int out_size, void* d_ws, size_t ws_size,
                              hipStream_t stream) {
    const float* x       = (const float*)d_in[0];
    const float* Wq      = (const float*)d_in[1];
    const float* bq      = (const float*)d_in[2];
    const float* Wk      = (const float*)d_in[3];
    const float* bk      = (const float*)d_in[4];
    const float* Wv      = (const float*)d_in[5];
    const float* bv      = (const float*)d_in[6];
    const float* Wl      = (const float*)d_in[7];
    const float* bl      = (const float*)d_in[8];
    const float* Wo      = (const float*)d_in[9];
    const float* bo      = (const float*)d_in[10];
    const float* Wp      = (const float*)d_in[11];
    const float* bp      = (const float*)d_in[12];
    const float* sch_dw  = (const float*)d_in[13];
    const float* sch_dwb = (const float*)d_in[14];
    const float* sch_pw  = (const float*)d_in[15];
    const float* sch_pwb = (const float*)d_in[16];
    const float* scv_dw  = (const float*)d_in[17];
    const float* scv_dwb = (const float*)d_in[18];
    const float* scv_pw  = (const float*)d_in[19];
    const float* scv_pwb = (const float*)d_in[20];
    const float* convh_w = (const float*)d_in[21];
    const float* convh_b = (const float*)d_in[22];
    const float* dsc_dw  = (const float*)d_in[23];
    const float* dsc_dwb = (const float*)d_in[24];
    const float* dsc_pw  = (const float*)d_in[25];
    const float* dsc_pwb = (const float*)d_in[26];
    const float* ln_g    = (const float*)d_in[27];
    const float* ln_b    = (const float*)d_in[28];

    float* ws = (float*)d_ws;
    const size_t SZ = (size_t)Bn * Np * Cn;   // 1,048,576 elements
    float* xp   = ws;                          // pooled BCHW; later p_norm
    float* xV   = ws + SZ;                     // BNC fp32; later dw3x3 out
    ushort_t* ghb = (ushort_t*)(ws + 2 * SZ);  // bf16 gh/gv (floats 2SZ..3SZ)
    ushort_t* gh  = ghb;
    ushort_t* gv  = ghb + SZ;
    float* f2   = ws + 2 * SZ;                 // dsc out (reuses gh/gv region later)
    ushort_t* bws  = (ushort_t*)(ws + 3 * SZ); // floats 3SZ..6SZ
    ushort_t* qb   = bws;
    ushort_t* kb_  = bws + SZ;
    ushort_t* vb   = bws + 2 * SZ;             // bf16 BNC (K layout)
    ushort_t* xKb  = bws + 3 * SZ;
    ushort_t* xVtb = bws + 4 * SZ;             // bf16 BCHW (V^T)
    ushort_t* xQb  = bws + 5 * SZ;
    ushort_t* OpB  = (ushort_t*)(ws + 6 * SZ); // bf16 partials, NSPLIT x SZ ushorts (floats 6SZ..10SZ)
    float* gap4k  = ws + 10 * SZ;                       // 4096
    float* Lpart  = gap4k + 4096;                       // NSPLIT*Bn*Np = 131072
    float* wcslot = Lpart + (size_t)NSPLIT * Bn * Np;
    ushort_t* Wc1b = (ushort_t*)wcslot;                 // 4096 ushorts
    ushort_t* Wc2b = Wc1b + 4096;                       // 4096 ushorts
    float* bcv  = wcslot + 4096;                        // 64 floats
    ushort_t* Wball = (ushort_t*)(bcv + 64);            // 7 x 4096 bf16 weights
    ushort_t* Wqb   = Wball;
    ushort_t* Wkb   = Wball + 4096;
    ushort_t* Wvb   = Wball + 8192;
    ushort_t* Wob   = Wball + 12288;
    ushort_t* Wlb   = Wball + 16384;
    ushort_t* Wpb   = Wball + 20480;
    ushort_t* Wdscb = Wball + 24576;

    dim3 g64(64, Bn);

    // 1) avgpool + GAP partials + weight combine + bf16 weight pre-convert
    avgpool_kernel<<<4096 + 32 + 112, 256, 0, stream>>>(x, xp, gap4k,
                                                  convh_w, convh_b, sch_pw, sch_pwb,
                                                  scv_pw, scv_pwb, Wc1b, Wc2b, bcv,
                                                  Wq, Wk, Wv, Wo, Wl, Wp, dsc_pw, Wball);
    // 2) qkv(+Wo) merged with dwpair (bf16 gh/gv)
    qkv_dw_kernel<<<dim3(64 + 256, Bn), 256, 0, stream>>>(
        xp, gap4k, Wqb, bq, Wkb, bk, Wvb, bv, Wob, bo,
        qb, kb_, vb, xV, xVtb, sch_dw, sch_dwb, scv_dw, scv_dwb, gh, gv);
    // 3) attention 1 merged with hpg (x_Q); attn blocks x<256 (4 waves each), hpg x>=256
    attn_hpg_kernel<<<dim3(256 + 64, Bn), 256, 0, stream>>>(
        qb, kb_, vb, OpB, Lpart, gh, gv, Wc1b, Wc2b, bcv, xQb);
    // 4) x_K = linear(combine(attn1), Wl)
    wl_mfma<<<g64, 256, 0, stream>>>(OpB, Lpart, Wlb, bl, xKb);
    // 5) attention 2 (same kernel, attn blocks only)
    attn_hpg_kernel<<<dim3(256, Bn), 256, 0, stream>>>(
        xQb, xKb, xVtb, OpB, Lpart, gh, gv, Wc1b, Wc2b, bcv, xQb);
    // 6) prompt = linear(combine, Wp) + x_V ; LN ; -> BCHW (xp reused as p_norm)
    linln_mfma<<<g64, 256, 0, stream>>>(OpB, Lpart, Wpb, bp, xV, ln_g, ln_b, xp);
    // 7) dsc depthwise 3x3 + GELU (xV reused as conv out)
    dw3x3_gelu_kernel<<<4096, 256, 0, stream>>>(xp, dsc_dw, dsc_dwb, xV);
    // 8) dsc 1x1 + residual
    dsc_mfma<<<g64, 256, 0, stream>>>(xV, Wdscb, dsc_pwb, xp, f2);
    // 9) bilinear x2
    upsample_kernel<<<4096, 256, 0, stream>>>(f2, (float*)d_out);
}

// Round 8
// 242.050 us; speedup vs baseline: 1.2201x; 1.2201x over previous
//
#include <hip/hip_runtime.h>
#include <math.h>

// Problem constants
#define Bn 4
#define Cn 64
#define Np 4096   // 64*64
#define NSPLIT 4
// SCALE * log2(e): folded into all Q pre-scales; attention uses exp2f (native v_exp_f32)
#define SCALE2 0.18033688011112042f

typedef unsigned short ushort_t;
typedef __attribute__((ext_vector_type(4))) float f32x4;
typedef __attribute__((ext_vector_type(8))) short bf16x8;
typedef __attribute__((ext_vector_type(4))) short bf16x4;

__device__ __forceinline__ float gelu_exact(float x) {
    return 0.5f * x * (1.0f + erff(x * 0.70710678118654752440f));
}
__device__ __forceinline__ ushort_t f2bf(float f) {       // RNE float->bf16
    unsigned int u = __float_as_uint(f);
    u += 0x7fffu + ((u >> 16) & 1u);
    return (ushort_t)(u >> 16);
}
__device__ __forceinline__ ushort_t f2bf_tr(float f) {    // truncating (1 VALU)
    return (ushort_t)(__float_as_uint(f) >> 16);
}
__device__ __forceinline__ float bf2f(ushort_t h) {
    return __uint_as_float(((unsigned int)h) << 16);
}
__device__ __forceinline__ void gload_lds16(const ushort_t* g, ushort_t* l) {
    __builtin_amdgcn_global_load_lds(
        (const __attribute__((address_space(1))) void*)g,
        (__attribute__((address_space(3))) void*)l, 16, 0, 0);
}
__device__ __forceinline__ bf16x8 cvt8(const float v[8]) {
    bf16x8 r;
    #pragma unroll
    for (int j = 0; j < 8; ++j) r[j] = (short)f2bf(v[j]);
    return r;
}
// bf16 pre-converted weights. Normal orientation: D[n][o].
__device__ __forceinline__ void gemm16b(const bf16x8 af[2], const ushort_t* __restrict__ Wb,
                                        int l16, int quad, f32x4* acc) {
    #pragma unroll
    for (int cb = 0; cb < 4; ++cb) {
        #pragma unroll
        for (int ks = 0; ks < 2; ++ks) {
            bf16x8 bw = *(const bf16x8*)(Wb + (cb * 16 + l16) * 64 + ks * 32 + quad * 8);
            acc[cb] = __builtin_amdgcn_mfma_f32_16x16x32_bf16(af[ks], bw, acc[cb], 0, 0, 0);
        }
    }
}
// Transposed orientation: D[o][n] -> ushort4 channel-packed stores.
__device__ __forceinline__ void gemm16Tb(const bf16x8 af[2], const ushort_t* __restrict__ Wb,
                                         int l16, int quad, f32x4* acc) {
    #pragma unroll
    for (int cb = 0; cb < 4; ++cb) {
        #pragma unroll
        for (int ks = 0; ks < 2; ++ks) {
            bf16x8 bw = *(const bf16x8*)(Wb + (cb * 16 + l16) * 64 + ks * 32 + quad * 8);
            acc[cb] = __builtin_amdgcn_mfma_f32_16x16x32_bf16(bw, af[ks], acc[cb], 0, 0, 0);
        }
    }
}
__device__ __forceinline__ void aload(const float* xs, int row, int quad, bf16x8 af[2]) {
    #pragma unroll
    for (int ks = 0; ks < 2; ++ks) {
        float v[8];
        #pragma unroll
        for (int j = 0; j < 8; ++j) v[j] = xs[(ks * 32 + quad * 8 + j) * 65 + row];
        af[ks] = cvt8(v);
    }
}
__device__ __forceinline__ void stage_bchw(const float* __restrict__ X, int b, int n0, int t,
                                           float* xs) {
    #pragma unroll
    for (int u = 0; u < 16; ++u) {
        int idx = t + u * 256;
        int c = idx >> 6, nl = idx & 63;
        xs[c * 65 + nl] = X[((size_t)(b * Cn + c)) * Np + n0 + nl];
    }
}
// combine NSPLIT bf16 attention partials * 1/l -> fp32 xs tile (vectorized ushort4 loads)
__device__ __forceinline__ void stage_comb(const ushort_t* __restrict__ OpB, const float* linv,
                                           int b, int n0, int t, float* xs) {
    const size_t SS = (size_t)Bn * Np * Cn;
    int c4 = (t & 15) * 4;
    #pragma unroll
    for (int u = 0; u < 4; ++u) {
        int nl = (t >> 4) + u * 16;
        size_t gi = ((size_t)(b * Np + n0 + nl)) * Cn + c4;
        ushort4 a0 = *(const ushort4*)(OpB + gi);
        ushort4 a1 = *(const ushort4*)(OpB + SS + gi);
        ushort4 a2 = *(const ushort4*)(OpB + 2 * SS + gi);
        ushort4 a3 = *(const ushort4*)(OpB + 3 * SS + gi);
        float li = linv[nl];
        xs[(c4 + 0) * 65 + nl] = (bf2f(a0.x) + bf2f(a1.x) + bf2f(a2.x) + bf2f(a3.x)) * li;
        xs[(c4 + 1) * 65 + nl] = (bf2f(a0.y) + bf2f(a1.y) + bf2f(a2.y) + bf2f(a3.y)) * li;
        xs[(c4 + 2) * 65 + nl] = (bf2f(a0.z) + bf2f(a1.z) + bf2f(a2.z) + bf2f(a3.z)) * li;
        xs[(c4 + 3) * 65 + nl] = (bf2f(a0.w) + bf2f(a1.w) + bf2f(a2.w) + bf2f(a3.w)) * li;
    }
}
__device__ __forceinline__ void store_bnc_T(ushort_t* __restrict__ Y, int b, int n, int quad,
                                            const f32x4* acc, const float* __restrict__ bias,
                                            float mult) {
    #pragma unroll
    for (int cb = 0; cb < 4; ++cb) {
        int o0 = cb * 16 + quad * 4;
        ushort4 pk;
        pk.x = f2bf((acc[cb][0] + bias[o0 + 0]) * mult);
        pk.y = f2bf((acc[cb][1] + bias[o0 + 1]) * mult);
        pk.z = f2bf((acc[cb][2] + bias[o0 + 2]) * mult);
        pk.w = f2bf((acc[cb][3] + bias[o0 + 3]) * mult);
        *(ushort4*)(Y + ((size_t)(b * Np + n)) * Cn + o0) = pk;
    }
}
__device__ __forceinline__ void store_bchw_bf16(ushort_t* __restrict__ Y, int b, int nb, int l16,
                                                const f32x4* acc, const float* __restrict__ bias) {
    #pragma unroll
    for (int cb = 0; cb < 4; ++cb) {
        int col = cb * 16 + l16;
        float bb = bias[col];
        ushort4 pk;
        pk.x = f2bf(acc[cb][0] + bb); pk.y = f2bf(acc[cb][1] + bb);
        pk.z = f2bf(acc[cb][2] + bb); pk.w = f2bf(acc[cb][3] + bb);
        *(ushort4*)(Y + ((size_t)(b * Cn + col)) * Np + nb) = pk;
    }
}

// ---------------------------------------------------------------- avgpool 2x2 + GAP partials + wcomb + weight bf16 pre-convert
__global__ void avgpool_kernel(const float* __restrict__ x, float* __restrict__ xp,
                               float* __restrict__ gap4k,
                               const float* __restrict__ convh_w, const float* __restrict__ convh_b,
                               const float* __restrict__ sch_pw, const float* __restrict__ sch_pwb,
                               const float* __restrict__ scv_pw, const float* __restrict__ scv_pwb,
                               ushort_t* __restrict__ Wc1b, ushort_t* __restrict__ Wc2b,
                               float* __restrict__ bcv,
                               const float* __restrict__ Wq, const float* __restrict__ Wk,
                               const float* __restrict__ Wv, const float* __restrict__ Wo,
                               const float* __restrict__ Wl, const float* __restrict__ Wp,
                               const float* __restrict__ dscpw, ushort_t* __restrict__ Wball) {
    if (blockIdx.x < 4096) {
        int idx = blockIdx.x * 256 + threadIdx.x;
        int j  = idx & 63;
        int i  = (idx >> 6) & 63;
        int bc = idx >> 12;
        const float* p = x + ((size_t)bc * 128 + 2 * i) * 128 + 2 * j;
        float v = 0.25f * (p[0] + p[1] + p[128] + p[129]);
        xp[idx] = v;
        float s = v;
        #pragma unroll
        for (int off = 1; off < 64; off <<= 1) s += __shfl_xor(s, off, 64);
        __shared__ float sm[4];
        if ((threadIdx.x & 63) == 0) sm[threadIdx.x >> 6] = s;
        __syncthreads();
        if (threadIdx.x == 0) gap4k[blockIdx.x] = sm[0] + sm[1] + sm[2] + sm[3];
    } else if (blockIdx.x < 4128) {
        int g = (blockIdx.x - 4096) * 256 + threadIdx.x;   // 8192 threads
        int sel = g >> 12, idx = g & 4095;
        int o = idx >> 6, c = idx & 63;
        const float* pw = sel ? scv_pw : sch_pw;
        float acc = 0.f;
        #pragma unroll 8
        for (int m = 0; m < 64; ++m) acc += convh_w[o * 64 + m] * pw[m * 64 + c];
        (sel ? Wc2b : Wc1b)[idx] = f2bf(acc * SCALE2);
        if (g < 64) {
            float ab = convh_b[g];
            for (int m = 0; m < 64; ++m) ab += convh_w[g * 64 + m] * (sch_pwb[m] + scv_pwb[m]);
            bcv[g] = ab * SCALE2;
        }
    } else {
        // pre-convert 7 weight matrices (4096 each) to bf16: Wq,Wk,Wv,Wo,Wl,Wp,dsc_pw
        int g = (blockIdx.x - 4128) * 256 + threadIdx.x;   // 28672 threads
        int which = g >> 12, idx = g & 4095;
        const float* srcs[7] = {Wq, Wk, Wv, Wo, Wl, Wp, dscpw};
        Wball[g] = f2bf(srcs[which][idx]);
    }
}

// ---------------------------------------------------------------- merged: QKV+Wo (x<64) | dwpair (x>=64)
__global__ __launch_bounds__(256) void qkv_dw_kernel(
    const float* __restrict__ xp, const float* __restrict__ gap4k,
    const ushort_t* __restrict__ Wqb, const float* __restrict__ bq,
    const ushort_t* __restrict__ Wkb, const float* __restrict__ bk,
    const ushort_t* __restrict__ Wvb, const float* __restrict__ bv,
    const ushort_t* __restrict__ Wob, const float* __restrict__ bo,
    ushort_t* __restrict__ qb, ushort_t* __restrict__ kb, ushort_t* __restrict__ vb,
    float* __restrict__ xV, ushort_t* __restrict__ xVtb,
    const float* __restrict__ wv5, const float* __restrict__ bv5,
    const float* __restrict__ wh5, const float* __restrict__ bh5,
    ushort_t* __restrict__ gh, ushort_t* __restrict__ gv) {
    int b = blockIdx.y, t = threadIdx.x;
    if (blockIdx.x >= 64) {
        // ---- dwpair: 4 consecutive elems/thread, float4 loads, bf16 outputs
        int part = blockIdx.x - 64;                  // 0..255
        int e = part * 1024 + t * 4;                 // within-batch offset
        size_t base = (size_t)b * (Cn * Np) + e;
        int c = e >> 12, i = (e >> 6) & 63, j = e & 63;
        const float* p = xp + ((size_t)(b * Cn + c)) * Np;
        float accV[4], accH[4];
        #pragma unroll
        for (int k = 0; k < 4; ++k) { accV[k] = bv5[c]; accH[k] = bh5[c]; }
        // vertical 5-tap: rows i-2..i+2, cols j..j+3 (float4)
        #pragma unroll
        for (int d = 0; d < 5; ++d) {
            int ii = i + d - 2;
            if (ii >= 0 && ii < 64) {
                f32x4 r = *(const f32x4*)(p + ii * 64 + j);
                float w = wv5[c * 5 + d];
                accV[0] += w * r[0]; accV[1] += w * r[1];
                accV[2] += w * r[2]; accV[3] += w * r[3];
            }
        }
        // horizontal 5-tap: row i, cols j-2..j+5
        f32x4 c0 = *(const f32x4*)(p + i * 64 + j);
        float col[8];
        col[2] = c0[0]; col[3] = c0[1]; col[4] = c0[2]; col[5] = c0[3];
        col[0] = (j >= 2)     ? p[i * 64 + j - 2] : 0.f;
        col[1] = (j >= 1)     ? p[i * 64 + j - 1] : 0.f;
        col[6] = (j + 4 < 64) ? p[i * 64 + j + 4] : 0.f;
        col[7] = (j + 5 < 64) ? p[i * 64 + j + 5] : 0.f;
        #pragma unroll
        for (int k = 0; k < 4; ++k) {
            #pragma unroll
            for (int d = 0; d < 5; ++d) accH[k] += wh5[c * 5 + d] * col[k + d];
        }
        ushort4 ph, pv_;
        ph.x = f2bf(gelu_exact(accV[0])); ph.y = f2bf(gelu_exact(accV[1]));
        ph.z = f2bf(gelu_exact(accV[2])); ph.w = f2bf(gelu_exact(accV[3]));
        pv_.x = f2bf(gelu_exact(accH[0])); pv_.y = f2bf(gelu_exact(accH[1]));
        pv_.z = f2bf(gelu_exact(accH[2])); pv_.w = f2bf(gelu_exact(accH[3]));
        *(ushort4*)(gh + base) = ph;
        *(ushort4*)(gv + base) = pv_;
        return;
    }
    // ---- QKV + Wo
    __shared__ float xs[64 * 65];
    __shared__ float gl[64];
    int n0 = blockIdx.x * 64;
    int wv_ = t >> 6, lane = t & 63, l16 = lane & 15, quad = lane >> 4;
    stage_bchw(xp, b, n0, t, xs);
    if (t < 64) {
        float s = 0.f;
        #pragma unroll
        for (int u = 0; u < 16; ++u) s += gap4k[(b * 64 + t) * 16 + u];
        gl[t] = s * (1.f / 4096.f);
    }
    __syncthreads();
    int row = wv_ * 16 + l16;
    int n   = n0 + wv_ * 16 + l16;
    int nb  = n0 + wv_ * 16 + quad * 4;
    bf16x8 ar[2], ag[2];
    #pragma unroll
    for (int ks = 0; ks < 2; ++ks) {
        float vr[8], vg[8];
        #pragma unroll
        for (int j = 0; j < 8; ++j) {
            int k = ks * 32 + quad * 8 + j;
            float xv = xs[k * 65 + row];
            vr[j] = xv; vg[j] = xv * gl[k];
        }
        ar[ks] = cvt8(vr); ag[ks] = cvt8(vg);
    }
    f32x4 acc[4];
    #pragma unroll
    for (int cb = 0; cb < 4; ++cb) acc[cb] = (f32x4){0.f, 0.f, 0.f, 0.f};
    gemm16Tb(ag, Wqb, l16, quad, acc);
    store_bnc_T(qb, b, n, quad, acc, bq, SCALE2);
    #pragma unroll
    for (int cb = 0; cb < 4; ++cb) acc[cb] = (f32x4){0.f, 0.f, 0.f, 0.f};
    gemm16Tb(ag, Wkb, l16, quad, acc);
    store_bnc_T(kb, b, n, quad, acc, bk, 1.f);
    #pragma unroll
    for (int cb = 0; cb < 4; ++cb) acc[cb] = (f32x4){0.f, 0.f, 0.f, 0.f};
    gemm16b(ag, Wvb, l16, quad, acc);
    store_bchw_bf16(vb, b, nb, l16, acc, bv);
    #pragma unroll
    for (int cb = 0; cb < 4; ++cb) acc[cb] = (f32x4){0.f, 0.f, 0.f, 0.f};
    gemm16b(ar, Wob, l16, quad, acc);
    #pragma unroll
    for (int cb = 0; cb < 4; ++cb) {
        int col = cb * 16 + l16;
        float bb = bo[col];
        ushort4 pk;
        float y0 = acc[cb][0] + bb, y1 = acc[cb][1] + bb, y2 = acc[cb][2] + bb, y3 = acc[cb][3] + bb;
        xV[((size_t)(b * Np + nb + 0)) * Cn + col] = y0;
        xV[((size_t)(b * Np + nb + 1)) * Cn + col] = y1;
        xV[((size_t)(b * Np + nb + 2)) * Cn + col] = y2;
        xV[((size_t)(b * Np + nb + 3)) * Cn + col] = y3;
        pk.x = f2bf(y0); pk.y = f2bf(y1); pk.z = f2bf(y2); pk.w = f2bf(y3);
        *(ushort4*)(xVtb + ((size_t)(b * Cn + col)) * Np + nb) = pk;
    }
}

// ---------------------------------------------------------------- attention body (device)
// 256 threads / 64 q-rows / 4 waves share staged 64-kv tiles. NSPLIT=4 splits.
// S^T orientation (register P), PV via 16x16x16, double-buffered global_load_lds.
// Swizzle key(r) = (r ^ (r>>3)) & 7 at 16B-chunk granularity.
// (Round-0 baseline structure: best measured attn dispatch, 44.0 us.)
__device__ __forceinline__ void attn_body(
    int xblk, int b, const ushort_t* __restrict__ Qb, const ushort_t* __restrict__ Kb,
    const ushort_t* __restrict__ Vtb, ushort_t* __restrict__ OpB, float* __restrict__ Lpart,
    ushort_t* smem) {
    ushort_t* kt0 = smem;            // [2][4096]
    ushort_t* vt0 = smem + 8192;     // [2][4096]
    int split = xblk >> 6;           // 0..3
    int qt    = xblk & 63;
    int n0    = qt * 64;
    int t     = threadIdx.x;         // 0..255
    int wave  = t >> 6, lane = t & 63;
    int l16   = lane & 15, quad = lane >> 4;

    const ushort_t* qp = Qb + ((size_t)(b * Np) + n0 + wave * 16 + l16) * Cn + quad * 8;
    bf16x8 aq0 = *(const bf16x8*)(qp);
    bf16x8 aq1 = *(const bf16x8*)(qp + 32);

    f32x4 oa[4];
    float psum = 0.f;
    #pragma unroll
    for (int db = 0; db < 4; ++db) oa[db] = (f32x4){0.f, 0.f, 0.f, 0.f};

    int lrow = lane >> 3;
    int kvbase = split * (Np / NSPLIT);      // 1024 kv per split
    const ushort_t* Kg = Qb == nullptr ? nullptr : Kb + ((size_t)b * Np) * Cn;
    const ushort_t* Vg = Vtb + ((size_t)b * Cn) * Np;

    auto stage = [&](int buf, int k0) {
        int wh = wave & 1;
        if (wave < 2) {
            ushort_t* dst = kt0 + buf * 4096 + wh * 2048;
            #pragma unroll
            for (int u = 0; u < 4; ++u) {
                int r = wh * 32 + u * 8 + lrow;
                int jsw = ((lane & 7) ^ lrow ^ (wh * 4 + u)) & 7;
                gload_lds16(Kg + ((size_t)(k0 + r)) * Cn + jsw * 8, dst + u * 512);
            }
        } else {
            ushort_t* dst = vt0 + buf * 4096 + wh * 2048;
            #pragma unroll
            for (int u = 0; u < 4; ++u) {
                int d = wh * 32 + u * 8 + lrow;
                int jsw = ((lane & 7) ^ lrow ^ (wh * 4 + u)) & 7;
                gload_lds16(Vg + (size_t)d * Np + k0 + jsw * 8, dst + u * 512);
            }
        }
    };
    const int NT = (Np / NSPLIT) / 64;       // 16
    stage(0, kvbase);
    __syncthreads();

    for (int m = 0; m < NT; ++m) {
        int cur = m & 1;
        if (m + 1 < NT) stage(1 - cur, kvbase + (m + 1) * 64);
        const ushort_t* ktc = kt0 + cur * 4096;
        const ushort_t* vtc = vt0 + cur * 4096;

        // S^T = K Q : C row = kv_sub, col = query(l16)
        f32x4 sa[4];
        #pragma unroll
        for (int cb = 0; cb < 4; ++cb) sa[cb] = (f32x4){0.f, 0.f, 0.f, 0.f};
        #pragma unroll
        for (int cb = 0; cb < 4; ++cb) {
            int key = ((l16 & 7) ^ (cb * 2 + (l16 >> 3))) & 7;
            const ushort_t* krow = ktc + (cb * 16 + l16) * 64;
            bf16x8 bk0 = *(const bf16x8*)(krow + ((quad    ) ^ key) * 8);
            bf16x8 bk1 = *(const bf16x8*)(krow + ((quad + 4) ^ key) * 8);
            sa[cb] = __builtin_amdgcn_mfma_f32_16x16x32_bf16(bk0, aq0, sa[cb], 0, 0, 0);
            sa[cb] = __builtin_amdgcn_mfma_f32_16x16x32_bf16(bk1, aq1, sa[cb], 0, 0, 0);
        }
        // p = 2^s; truncating bf16 pack straight into PV B-fragments
        bf16x4 pb[4];
        #pragma unroll
        for (int cb = 0; cb < 4; ++cb) {
            float p0 = exp2f(sa[cb][0]), p1 = exp2f(sa[cb][1]);
            float p2 = exp2f(sa[cb][2]), p3 = exp2f(sa[cb][3]);
            psum += (p0 + p1) + (p2 + p3);
            bf16x4 pk;
            pk[0] = (short)f2bf_tr(p0); pk[1] = (short)f2bf_tr(p1);
            pk[2] = (short)f2bf_tr(p2); pk[3] = (short)f2bf_tr(p3);
            pb[cb] = pk;
        }
        // O^T += V^T P^T
        #pragma unroll
        for (int kc = 0; kc < 4; ++kc) {
            #pragma unroll
            for (int db = 0; db < 4; ++db) {
                int d = db * 16 + l16;
                int key = ((l16 & 7) ^ (db * 2 + (l16 >> 3))) & 7;
                int phys = (kc * 2 + (quad >> 1)) ^ key;
                const ushort_t* va = vtc + d * 64 + phys * 8 + (quad & 1) * 4;
                bf16x4 av = *(const bf16x4*)va;
                oa[db] = __builtin_amdgcn_mfma_f32_16x16x16bf16_1k(av, pb[kc], oa[db], 0, 0, 0);
            }
        }
        __syncthreads();
    }
    psum += __shfl_xor(psum, 16, 64);
    psum += __shfl_xor(psum, 32, 64);
    size_t obase = ((size_t)(split * Bn + b)) * Np;
    int n = n0 + wave * 16 + l16;
    if (quad == 0) Lpart[obase + n] = psum;
    #pragma unroll
    for (int db = 0; db < 4; ++db) {
        ushort4 pk;
        pk.x = f2bf(oa[db][0]); pk.y = f2bf(oa[db][1]);
        pk.z = f2bf(oa[db][2]); pk.w = f2bf(oa[db][3]);
        *(ushort4*)(OpB + (obase + n) * Cn + db * 16 + quad * 4) = pk;
    }
}

// hpg body: bf16 gh/gv staged [n][c] stride 72, combined 1x1 (SCALE2 folded, bf16 weights) -> xQb
__device__ __forceinline__ void hpg_body(
    int tile, int b, const ushort_t* __restrict__ gh, const ushort_t* __restrict__ gv,
    const ushort_t* __restrict__ Wc1b, const ushort_t* __restrict__ Wc2b,
    const float* __restrict__ bcv,
    ushort_t* __restrict__ xQb, ushort_t* smem) {
    ushort_t* xs1 = smem;            // 64 x 72
    ushort_t* xs2 = smem + 4608;
    int n0 = tile * 64, t = threadIdx.x;
    int wv_ = t >> 6, lane = t & 63, l16 = lane & 15, quad = lane >> 4;
    #pragma unroll
    for (int u = 0; u < 4; ++u) {
        int lin = u * 256 + t;
        int c = lin >> 4, nl4 = (lin & 15) * 4;
        size_t gi = ((size_t)(b * Cn + c)) * Np + n0 + nl4;
        ushort4 g1 = *(const ushort4*)(gh + gi);
        ushort4 g2 = *(const ushort4*)(gv + gi);
        xs1[(nl4 + 0) * 72 + c] = g1.x; xs1[(nl4 + 1) * 72 + c] = g1.y;
        xs1[(nl4 + 2) * 72 + c] = g1.z; xs1[(nl4 + 3) * 72 + c] = g1.w;
        xs2[(nl4 + 0) * 72 + c] = g2.x; xs2[(nl4 + 1) * 72 + c] = g2.y;
        xs2[(nl4 + 2) * 72 + c] = g2.z; xs2[(nl4 + 3) * 72 + c] = g2.w;
    }
    __syncthreads();
    int row = wv_ * 16 + l16;
    bf16x8 a1[2], a2[2];
    #pragma unroll
    for (int ks = 0; ks < 2; ++ks) {
        a1[ks] = *(const bf16x8*)(xs1 + row * 72 + ks * 32 + quad * 8);
        a2[ks] = *(const bf16x8*)(xs2 + row * 72 + ks * 32 + quad * 8);
    }
    f32x4 acc[4];
    #pragma unroll
    for (int cb = 0; cb < 4; ++cb) acc[cb] = (f32x4){0.f, 0.f, 0.f, 0.f};
    gemm16Tb(a1, Wc1b, l16, quad, acc);
    gemm16Tb(a2, Wc2b, l16, quad, acc);
    store_bnc_T(xQb, b, n0 + wv_ * 16 + l16, quad, acc, bcv, 1.f);
}

// merged launch: x<256 -> attention ; x>=256 -> hpg tile (x-256)
__global__ __launch_bounds__(256) void attn_hpg_kernel(
    const ushort_t* __restrict__ Qb, const ushort_t* __restrict__ Kb,
    const ushort_t* __restrict__ Vtb, ushort_t* __restrict__ OpB, float* __restrict__ Lpart,
    const ushort_t* __restrict__ gh, const ushort_t* __restrict__ gv,
    const ushort_t* __restrict__ Wc1b, const ushort_t* __restrict__ Wc2b,
    const float* __restrict__ bcv, ushort_t* __restrict__ xQb) {
    __shared__ ushort_t smem[16384];   // attn: 2x(4096+4096); hpg: 2x4608
    int b = blockIdx.y;
    if (blockIdx.x < 256)
        attn_body(blockIdx.x, b, Qb, Kb, Vtb, OpB, Lpart, smem);
    else
        hpg_body(blockIdx.x - 256, b, gh, gv, Wc1b, Wc2b, bcv, xQb, smem);
}

// ---------------------------------------------------------------- combine(attn1)+Wl -> xKb
__global__ __launch_bounds__(256) void wl_mfma(
    const ushort_t* __restrict__ OpB, const float* __restrict__ Lp,
    const ushort_t* __restrict__ Wlb, const float* __restrict__ bl, ushort_t* __restrict__ xKb) {
    __shared__ float xs[64 * 65];
    __shared__ float linv[64];
    int b = blockIdx.y, n0 = blockIdx.x * 64, t = threadIdx.x;
    int wv_ = t >> 6, lane = t & 63, l16 = lane & 15, quad = lane >> 4;
    if (t < 64) {
        size_t li = (size_t)b * Np + n0 + t;
        const size_t LS = (size_t)Bn * Np;
        linv[t] = 1.f / (Lp[li] + Lp[LS + li] + Lp[2 * LS + li] + Lp[3 * LS + li]);
    }
    __syncthreads();
    stage_comb(OpB, linv, b, n0, t, xs);
    __syncthreads();
    bf16x8 af[2];
    aload(xs, wv_ * 16 + l16, quad, af);
    f32x4 acc[4];
    #pragma unroll
    for (int cb = 0; cb < 4; ++cb) acc[cb] = (f32x4){0.f, 0.f, 0.f, 0.f};
    gemm16Tb(af, Wlb, l16, quad, acc);
    store_bnc_T(xKb, b, n0 + wv_ * 16 + l16, quad, acc, bl, 1.f);
}

// ---------------------------------------------------------------- combine(attn2)+Wp+res+LayerNorm -> BCHW
__global__ __launch_bounds__(256) void linln_mfma(
    const ushort_t* __restrict__ OpB, const float* __restrict__ Lp,
    const ushort_t* __restrict__ Wpb, const float* __restrict__ bp,
    const float* __restrict__ xV, const float* __restrict__ g, const float* __restrict__ beta,
    float* __restrict__ out) {
    __shared__ float xs[64 * 65];
    __shared__ float linv[64];
    int b = blockIdx.y, n0 = blockIdx.x * 64, t = threadIdx.x;
    int wv_ = t >> 6, lane = t & 63, l16 = lane & 15, quad = lane >> 4;
    if (t < 64) {
        size_t li = (size_t)b * Np + n0 + t;
        const size_t LS = (size_t)Bn * Np;
        linv[t] = 1.f / (Lp[li] + Lp[LS + li] + Lp[2 * LS + li] + Lp[3 * LS + li]);
    }
    __syncthreads();
    stage_comb(OpB, linv, b, n0, t, xs);
    __syncthreads();
    bf16x8 af[2];
    aload(xs, wv_ * 16 + l16, quad, af);
    f32x4 acc[4];
    #pragma unroll
    for (int cb = 0; cb < 4; ++cb) acc[cb] = (f32x4){0.f, 0.f, 0.f, 0.f};
    gemm16b(af, Wpb, l16, quad, acc);
    int nb = n0 + wv_ * 16 + quad * 4;
    float vals[4][4], gc[4], bec[4];
    #pragma unroll
    for (int cb = 0; cb < 4; ++cb) {
        int col = cb * 16 + l16;
        float bb = bp[col];
        gc[cb] = g[col]; bec[cb] = beta[col];
        #pragma unroll
        for (int r = 0; r < 4; ++r)
            vals[cb][r] = acc[cb][r] + bb + xV[((size_t)(b * Np + nb + r)) * Cn + col];
    }
    f32x4 yn[4];
    #pragma unroll
    for (int r = 0; r < 4; ++r) {
        float s = 0.f, s2 = 0.f;
        #pragma unroll
        for (int cb = 0; cb < 4; ++cb) { s += vals[cb][r]; s2 += vals[cb][r] * vals[cb][r]; }
        #pragma unroll
        for (int off = 1; off < 16; off <<= 1) {
            s  += __shfl_xor(s, off, 64);
            s2 += __shfl_xor(s2, off, 64);
        }
        float mu  = s * (1.f / 64.f);
        float var = s2 * (1.f / 64.f) - mu * mu;
        float ivs = rsqrtf(var + 1e-5f);
        #pragma unroll
        for (int cb = 0; cb < 4; ++cb)
            yn[cb][r] = (vals[cb][r] - mu) * ivs * gc[cb] + bec[cb];
    }
    #pragma unroll
    for (int cb = 0; cb < 4; ++cb)
        *(f32x4*)(out + ((size_t)(b * Cn + cb * 16 + l16)) * Np + nb) = yn[cb];
}

// ---------------------------------------------------------------- dw3x3 + GELU (elementwise)
__global__ void dw3x3_gelu_kernel(const float* __restrict__ xin, const float* __restrict__ w,
                                  const float* __restrict__ bias, float* __restrict__ out) {
    int idx = blockIdx.x * 256 + threadIdx.x;
    int j = idx & 63, i = (idx >> 6) & 63, bc = idx >> 12, c = bc & 63;
    const float* p = xin + (size_t)bc * Np;
    float acc = bias[c];
    #pragma unroll
    for (int dy = 0; dy < 3; ++dy) {
        int ii = i + dy - 1;
        if (ii < 0 || ii >= 64) continue;
        #pragma unroll
        for (int dx = 0; dx < 3; ++dx) {
            int jj = j + dx - 1;
            if (jj < 0 || jj >= 64) continue;
            acc += w[c * 9 + dy * 3 + dx] * p[ii * 64 + jj];
        }
    }
    out[idx] = gelu_exact(acc);
}

// ---------------------------------------------------------------- dsc 1x1 (bf16 weights) + residual -> BCHW
__global__ __launch_bounds__(256) void dsc_mfma(
    const float* __restrict__ X, const ushort_t* __restrict__ Wb, const float* __restrict__ bias,
    const float* __restrict__ res, float* __restrict__ out) {
    __shared__ float xs[64 * 65];
    int b = blockIdx.y, n0 = blockIdx.x * 64, t = threadIdx.x;
    int wv_ = t >> 6, lane = t & 63, l16 = lane & 15, quad = lane >> 4;
    stage_bchw(X, b, n0, t, xs);
    __syncthreads();
    bf16x8 af[2];
    aload(xs, wv_ * 16 + l16, quad, af);
    f32x4 acc[4];
    #pragma unroll
    for (int cb = 0; cb < 4; ++cb) acc[cb] = (f32x4){0.f, 0.f, 0.f, 0.f};
    gemm16b(af, Wb, l16, quad, acc);
    int nb = n0 + wv_ * 16 + quad * 4;
    #pragma unroll
    for (int cb = 0; cb < 4; ++cb) {
        int col = cb * 16 + l16;
        float bb = bias[col];
        size_t oi = ((size_t)(b * Cn + col)) * Np + nb;
        f32x4 rv = *(const f32x4*)(res + oi);
        f32x4 v4;
        #pragma unroll
        for (int r = 0; r < 4; ++r) v4[r] = acc[cb][r] + bb + rv[r];
        *(f32x4*)(out + oi) = v4;
    }
}

// ---------------------------------------------------------------- bilinear x2 upsample (4 outs/thread)
__global__ void upsample_kernel(const float* __restrict__ in, float* __restrict__ out) {
    int idx = blockIdx.x * 256 + threadIdx.x;     // 1,048,576 threads
    int x4 = (idx & 31) * 4;
    int y  = (idx >> 5) & 127;
    int bc = idx >> 12;
    float sy = y * (63.f / 127.f);
    int y0 = (int)sy;
    float fy = sy - y0;
    int y1 = min(y0 + 1, 63);
    const float* p0 = in + (size_t)bc * Np + y0 * 64;
    const float* p1 = in + (size_t)bc * Np + y1 * 64;
    f32x4 o;
    #pragma unroll
    for (int k = 0; k < 4; ++k) {
        int xo = x4 + k;
        float sx = xo * (63.f / 127.f);
        int x0 = (int)sx;
        float fx = sx - x0;
        int x1 = min(x0 + 1, 63);
        float r0 = p0[x0] + (p0[x1] - p0[x0]) * fx;
        float r1 = p1[x0] + (p1[x1] - p1[x0]) * fx;
        o[k] = r0 + (r1 - r0) * fy;
    }
    *(f32x4*)(out + (size_t)idx * 4) = o;
}

// ----------------------------------------------------------------
extern "C" void kernel_launch(void* const* d_in, const int* in_sizes, int n_in,
                              void* d_out, int out_size, void* d_ws, size_t ws_size,
                              hipStream_t stream) {
    const float* x       = (const float*)d_in[0];
    const float* Wq      = (const float*)d_in[1];
    const float* bq      = (const float*)d_in[2];
    const float* Wk      = (const float*)d_in[3];
    const float* bk      = (const float*)d_in[4];
    const float* Wv      = (const float*)d_in[5];
    const float* bv      = (const float*)d_in[6];
    const float* Wl      = (const float*)d_in[7];
    const float* bl      = (const float*)d_in[8];
    const float* Wo      = (const float*)d_in[9];
    const float* bo      = (const float*)d_in[10];
    const float* Wp      = (const float*)d_in[11];
    const float* bp      = (const float*)d_in[12];
    const float* sch_dw  = (const float*)d_in[13];
    const float* sch_dwb = (const float*)d_in[14];
    const float* sch_pw  = (const float*)d_in[15];
    const float* sch_pwb = (const float*)d_in[16];
    const float* scv_dw  = (const float*)d_in[17];
    const float* scv_dwb = (const float*)d_in[18];
    const float* scv_pw  = (const float*)d_in[19];
    const float* scv_pwb = (const float*)d_in[20];
    const float* convh_w = (const float*)d_in[21];
    const float* convh_b = (const float*)d_in[22];
    const float* dsc_dw  = (const float*)d_in[23];
    const float* dsc_dwb = (const float*)d_in[24];
    const float* dsc_pw  = (const float*)d_in[25];
    const float* dsc_pwb = (const float*)d_in[26];
    const float* ln_g    = (const float*)d_in[27];
    const float* ln_b    = (const float*)d_in[28];

    float* ws = (float*)d_ws;
    const size_t SZ = (size_t)Bn * Np * Cn;   // 1,048,576 elements
    float* xp   = ws;                          // pooled BCHW; later p_norm
    float* xV   = ws + SZ;                     // BNC fp32; later dw3x3 out
    ushort_t* ghb = (ushort_t*)(ws + 2 * SZ);  // bf16 gh/gv (floats 2SZ..3SZ)
    ushort_t* gh  = ghb;
    ushort_t* gv  = ghb + SZ;
    float* f2   = ws + 2 * SZ;                 // dsc out (reuses gh/gv region later)
    ushort_t* bws  = (ushort_t*)(ws + 3 * SZ); // floats 3SZ..6SZ
    ushort_t* qb   = bws;
    ushort_t* kb_  = bws + SZ;
    ushort_t* vb   = bws + 2 * SZ;             // bf16 BCHW (V^T)
    ushort_t* xKb  = bws + 3 * SZ;
    ushort_t* xVtb = bws + 4 * SZ;             // bf16 BCHW (V^T)
    ushort_t* xQb  = bws + 5 * SZ;
    ushort_t* OpB  = (ushort_t*)(ws + 6 * SZ); // bf16 partials, 4 x SZ ushorts (floats 6SZ..8SZ)
    float* gap4k  = ws + 8 * SZ;                        // 4096
    float* Lpart  = gap4k + 4096;                       // NSPLIT*Bn*Np = 65536
    float* wcslot = Lpart + (size_t)NSPLIT * Bn * Np;
    ushort_t* Wc1b = (ushort_t*)wcslot;                 // 4096 ushorts
    ushort_t* Wc2b = Wc1b + 4096;                       // 4096 ushorts (8192 us = 4096 floats)
    float* bcv  = wcslot + 4096;                        // 64 floats
    ushort_t* Wball = (ushort_t*)(bcv + 64);            // 7 x 4096 bf16 weights
    ushort_t* Wqb   = Wball;
    ushort_t* Wkb   = Wball + 4096;
    ushort_t* Wvb   = Wball + 8192;
    ushort_t* Wob   = Wball + 12288;
    ushort_t* Wlb   = Wball + 16384;
    ushort_t* Wpb   = Wball + 20480;
    ushort_t* Wdscb = Wball + 24576;

    dim3 g64(64, Bn);

    // 1) avgpool + GAP partials + weight combine + bf16 weight pre-convert
    avgpool_kernel<<<4096 + 32 + 112, 256, 0, stream>>>(x, xp, gap4k,
                                                  convh_w, convh_b, sch_pw, sch_pwb,
                                                  scv_pw, scv_pwb, Wc1b, Wc2b, bcv,
                                                  Wq, Wk, Wv, Wo, Wl, Wp, dsc_pw, Wball);
    // 2) qkv(+Wo) merged with dwpair (bf16 gh/gv)
    qkv_dw_kernel<<<dim3(64 + 256, Bn), 256, 0, stream>>>(
        xp, gap4k, Wqb, bq, Wkb, bk, Wvb, bv, Wob, bo,
        qb, kb_, vb, xV, xVtb, sch_dw, sch_dwb, scv_dw, scv_dwb, gh, gv);
    // 3) attention 1 merged with hpg (x_Q)
    attn_hpg_kernel<<<dim3(256 + 64, Bn), 256, 0, stream>>>(
        qb, kb_, vb, OpB, Lpart, gh, gv, Wc1b, Wc2b, bcv, xQb);
    // 4) x_K = linear(combine(attn1), Wl)
    wl_mfma<<<g64, 256, 0, stream>>>(OpB, Lpart, Wlb, bl, xKb);
    // 5) attention 2 (same kernel, attn blocks only)
    attn_hpg_kernel<<<dim3(256, Bn), 256, 0, stream>>>(
        xQb, xKb, xVtb, OpB, Lpart, gh, gv, Wc1b, Wc2b, bcv, xQb);
    // 6) prompt = linear(combine, Wp) + x_V ; LN ; -> BCHW (xp reused as p_norm)
    linln_mfma<<<g64, 256, 0, stream>>>(OpB, Lpart, Wpb, bp, xV, ln_g, ln_b, xp);
    // 7) dsc depthwise (xV reused as conv out)
    dw3x3_gelu_kernel<<<4096, 256, 0, stream>>>(xp, dsc_dw, dsc_dwb, xV);
    // 8) dsc 1x1 + residual
    dsc_mfma<<<g64, 256, 0, stream>>>(xV, Wdscb, dsc_pwb, xp, f2);
    // 9) bilinear x2
    upsample_kernel<<<4096, 256, 0, stream>>>(f2, (float*)d_out);
}

// Round 9
// 235.504 us; speedup vs baseline: 1.2540x; 1.0278x over previous
//
#include <hip/hip_runtime.h>
#include <math.h>

// Problem constants
#define Bn 4
#define Cn 64
#define Np 4096   // 64*64
#define NSPLIT 4
// SCALE * log2(e): folded into all Q pre-scales; attention uses exp2f (native v_exp_f32)
#define SCALE2 0.18033688011112042f

typedef unsigned short ushort_t;
typedef __attribute__((ext_vector_type(4))) float f32x4;
typedef __attribute__((ext_vector_type(2))) float f32x2;
typedef __attribute__((ext_vector_type(8))) short bf16x8;
typedef __attribute__((ext_vector_type(4))) short bf16x4;

__device__ __forceinline__ float gelu_exact(float x) {
    return 0.5f * x * (1.0f + erff(x * 0.70710678118654752440f));
}
__device__ __forceinline__ ushort_t f2bf(float f) {       // RNE float->bf16
    unsigned int u = __float_as_uint(f);
    u += 0x7fffu + ((u >> 16) & 1u);
    return (ushort_t)(u >> 16);
}
__device__ __forceinline__ ushort_t f2bf_tr(float f) {    // truncating (1 VALU)
    return (ushort_t)(__float_as_uint(f) >> 16);
}
__device__ __forceinline__ float bf2f(ushort_t h) {
    return __uint_as_float(((unsigned int)h) << 16);
}
__device__ __forceinline__ void gload_lds16(const ushort_t* g, ushort_t* l) {
    __builtin_amdgcn_global_load_lds(
        (const __attribute__((address_space(1))) void*)g,
        (__attribute__((address_space(3))) void*)l, 16, 0, 0);
}
__device__ __forceinline__ bf16x8 cvt8(const float v[8]) {
    bf16x8 r;
    #pragma unroll
    for (int j = 0; j < 8; ++j) r[j] = (short)f2bf(v[j]);
    return r;
}
// bf16 pre-converted weights. Normal orientation: D[n][o].
__device__ __forceinline__ void gemm16b(const bf16x8 af[2], const ushort_t* __restrict__ Wb,
                                        int l16, int quad, f32x4* acc) {
    #pragma unroll
    for (int cb = 0; cb < 4; ++cb) {
        #pragma unroll
        for (int ks = 0; ks < 2; ++ks) {
            bf16x8 bw = *(const bf16x8*)(Wb + (cb * 16 + l16) * 64 + ks * 32 + quad * 8);
            acc[cb] = __builtin_amdgcn_mfma_f32_16x16x32_bf16(af[ks], bw, acc[cb], 0, 0, 0);
        }
    }
}
// Transposed orientation: D[o][n] -> ushort4 channel-packed stores.
__device__ __forceinline__ void gemm16Tb(const bf16x8 af[2], const ushort_t* __restrict__ Wb,
                                         int l16, int quad, f32x4* acc) {
    #pragma unroll
    for (int cb = 0; cb < 4; ++cb) {
        #pragma unroll
        for (int ks = 0; ks < 2; ++ks) {
            bf16x8 bw = *(const bf16x8*)(Wb + (cb * 16 + l16) * 64 + ks * 32 + quad * 8);
            acc[cb] = __builtin_amdgcn_mfma_f32_16x16x32_bf16(bw, af[ks], acc[cb], 0, 0, 0);
        }
    }
}
__device__ __forceinline__ void aload(const float* xs, int row, int quad, bf16x8 af[2]) {
    #pragma unroll
    for (int ks = 0; ks < 2; ++ks) {
        float v[8];
        #pragma unroll
        for (int j = 0; j < 8; ++j) v[j] = xs[(ks * 32 + quad * 8 + j) * 65 + row];
        af[ks] = cvt8(v);
    }
}
// float4 global loads (4x fewer VMEM insts); 4 scalar LDS writes each (pad-65 layout)
__device__ __forceinline__ void stage_bchw4(const float* __restrict__ X, int b, int n0, int t,
                                            float* xs) {
    #pragma unroll
    for (int u = 0; u < 4; ++u) {
        int base = u * 1024 + t * 4;
        int c = base >> 6, nl = base & 63;
        f32x4 v = *(const f32x4*)(X + ((size_t)(b * Cn + c)) * Np + n0 + nl);
        xs[c * 65 + nl + 0] = v[0];
        xs[c * 65 + nl + 1] = v[1];
        xs[c * 65 + nl + 2] = v[2];
        xs[c * 65 + nl + 3] = v[3];
    }
}
// combine NSPLIT bf16 attention partials * 1/l -> fp32 xs tile (vectorized ushort4 loads)
__device__ __forceinline__ void stage_comb(const ushort_t* __restrict__ OpB, const float* linv,
                                           int b, int n0, int t, float* xs) {
    const size_t SS = (size_t)Bn * Np * Cn;
    int c4 = (t & 15) * 4;
    #pragma unroll
    for (int u = 0; u < 4; ++u) {
        int nl = (t >> 4) + u * 16;
        size_t gi = ((size_t)(b * Np + n0 + nl)) * Cn + c4;
        ushort4 a0 = *(const ushort4*)(OpB + gi);
        ushort4 a1 = *(const ushort4*)(OpB + SS + gi);
        ushort4 a2 = *(const ushort4*)(OpB + 2 * SS + gi);
        ushort4 a3 = *(const ushort4*)(OpB + 3 * SS + gi);
        float li = linv[nl];
        xs[(c4 + 0) * 65 + nl] = (bf2f(a0.x) + bf2f(a1.x) + bf2f(a2.x) + bf2f(a3.x)) * li;
        xs[(c4 + 1) * 65 + nl] = (bf2f(a0.y) + bf2f(a1.y) + bf2f(a2.y) + bf2f(a3.y)) * li;
        xs[(c4 + 2) * 65 + nl] = (bf2f(a0.z) + bf2f(a1.z) + bf2f(a2.z) + bf2f(a3.z)) * li;
        xs[(c4 + 3) * 65 + nl] = (bf2f(a0.w) + bf2f(a1.w) + bf2f(a2.w) + bf2f(a3.w)) * li;
    }
}
__device__ __forceinline__ void store_bnc_T(ushort_t* __restrict__ Y, int b, int n, int quad,
                                            const f32x4* acc, const float* __restrict__ bias,
                                            float mult) {
    #pragma unroll
    for (int cb = 0; cb < 4; ++cb) {
        int o0 = cb * 16 + quad * 4;
        ushort4 pk;
        pk.x = f2bf((acc[cb][0] + bias[o0 + 0]) * mult);
        pk.y = f2bf((acc[cb][1] + bias[o0 + 1]) * mult);
        pk.z = f2bf((acc[cb][2] + bias[o0 + 2]) * mult);
        pk.w = f2bf((acc[cb][3] + bias[o0 + 3]) * mult);
        *(ushort4*)(Y + ((size_t)(b * Np + n)) * Cn + o0) = pk;
    }
}
__device__ __forceinline__ void store_bchw_bf16(ushort_t* __restrict__ Y, int b, int nb, int l16,
                                                const f32x4* acc, const float* __restrict__ bias) {
    #pragma unroll
    for (int cb = 0; cb < 4; ++cb) {
        int col = cb * 16 + l16;
        float bb = bias[col];
        ushort4 pk;
        pk.x = f2bf(acc[cb][0] + bb); pk.y = f2bf(acc[cb][1] + bb);
        pk.z = f2bf(acc[cb][2] + bb); pk.w = f2bf(acc[cb][3] + bb);
        *(ushort4*)(Y + ((size_t)(b * Cn + col)) * Np + nb) = pk;
    }
}

// ---------------------------------------------------------------- avgpool 2x2 (float4, 2 outs/thread) + GAP partials + wcomb + weight bf16 pre-convert
__global__ void avgpool_kernel(const float* __restrict__ x, float* __restrict__ xp,
                               float* __restrict__ gap4k,
                               const float* __restrict__ convh_w, const float* __restrict__ convh_b,
                               const float* __restrict__ sch_pw, const float* __restrict__ sch_pwb,
                               const float* __restrict__ scv_pw, const float* __restrict__ scv_pwb,
                               ushort_t* __restrict__ Wc1b, ushort_t* __restrict__ Wc2b,
                               float* __restrict__ bcv,
                               const float* __restrict__ Wq, const float* __restrict__ Wk,
                               const float* __restrict__ Wv, const float* __restrict__ Wo,
                               const float* __restrict__ Wl, const float* __restrict__ Wp,
                               const float* __restrict__ dscpw, ushort_t* __restrict__ Wball) {
    if (blockIdx.x < 2048) {
        int gid = blockIdx.x * 256 + threadIdx.x;     // 524288 threads, 2 outputs each
        int j2 = gid & 31;                             // output col pair
        int i  = (gid >> 5) & 63;                      // output row
        int bc = gid >> 11;
        const float* p = x + ((size_t)bc * 128 + 2 * i) * 128 + 4 * j2;
        f32x4 r0 = *(const f32x4*)(p);
        f32x4 r1 = *(const f32x4*)(p + 128);
        float o0 = 0.25f * (r0[0] + r0[1] + r1[0] + r1[1]);
        float o1 = 0.25f * (r0[2] + r0[3] + r1[2] + r1[3]);
        f32x2 ov; ov[0] = o0; ov[1] = o1;
        *(f32x2*)(xp + (size_t)bc * Np + i * 64 + j2 * 2) = ov;
        float s = o0 + o1;
        #pragma unroll
        for (int off = 1; off < 64; off <<= 1) s += __shfl_xor(s, off, 64);
        __shared__ float sm[4];
        if ((threadIdx.x & 63) == 0) sm[threadIdx.x >> 6] = s;
        __syncthreads();
        if (threadIdx.x == 0) gap4k[blockIdx.x] = sm[0] + sm[1] + sm[2] + sm[3];   // 8 partials/image
    } else if (blockIdx.x < 2080) {
        int g = (blockIdx.x - 2048) * 256 + threadIdx.x;   // 8192 threads
        int sel = g >> 12, idx = g & 4095;
        int o = idx >> 6, c = idx & 63;
        const float* pw = sel ? scv_pw : sch_pw;
        float acc = 0.f;
        #pragma unroll 8
        for (int m = 0; m < 64; ++m) acc += convh_w[o * 64 + m] * pw[m * 64 + c];
        (sel ? Wc2b : Wc1b)[idx] = f2bf(acc * SCALE2);
        if (g < 64) {
            float ab = convh_b[g];
            for (int m = 0; m < 64; ++m) ab += convh_w[g * 64 + m] * (sch_pwb[m] + scv_pwb[m]);
            bcv[g] = ab * SCALE2;
        }
    } else {
        // pre-convert 7 weight matrices (4096 each) to bf16: Wq,Wk,Wv,Wo,Wl,Wp,dsc_pw
        int g = (blockIdx.x - 2080) * 256 + threadIdx.x;   // 28672 threads
        int which = g >> 12, idx = g & 4095;
        const float* srcs[7] = {Wq, Wk, Wv, Wo, Wl, Wp, dscpw};
        Wball[g] = f2bf(srcs[which][idx]);
    }
}

// ---------------------------------------------------------------- merged: QKV+Wo (x<64) | dwpair (x>=64)
__global__ __launch_bounds__(256) void qkv_dw_kernel(
    const float* __restrict__ xp, const float* __restrict__ gap4k,
    const ushort_t* __restrict__ Wqb, const float* __restrict__ bq,
    const ushort_t* __restrict__ Wkb, const float* __restrict__ bk,
    const ushort_t* __restrict__ Wvb, const float* __restrict__ bv,
    const ushort_t* __restrict__ Wob, const float* __restrict__ bo,
    ushort_t* __restrict__ qb, ushort_t* __restrict__ kb, ushort_t* __restrict__ vb,
    float* __restrict__ xV, ushort_t* __restrict__ xVtb,
    const float* __restrict__ wv5, const float* __restrict__ bv5,
    const float* __restrict__ wh5, const float* __restrict__ bh5,
    ushort_t* __restrict__ gh, ushort_t* __restrict__ gv) {
    int b = blockIdx.y, t = threadIdx.x;
    if (blockIdx.x >= 64) {
        // ---- dwpair: 4 consecutive elems/thread, float4 loads, bf16 outputs
        int part = blockIdx.x - 64;                  // 0..255
        int e = part * 1024 + t * 4;                 // within-batch offset
        size_t base = (size_t)b * (Cn * Np) + e;
        int c = e >> 12, i = (e >> 6) & 63, j = e & 63;
        const float* p = xp + ((size_t)(b * Cn + c)) * Np;
        float accV[4], accH[4];
        #pragma unroll
        for (int k = 0; k < 4; ++k) { accV[k] = bv5[c]; accH[k] = bh5[c]; }
        // vertical 5-tap: rows i-2..i+2, cols j..j+3 (float4)
        #pragma unroll
        for (int d = 0; d < 5; ++d) {
            int ii = i + d - 2;
            if (ii >= 0 && ii < 64) {
                f32x4 r = *(const f32x4*)(p + ii * 64 + j);
                float w = wv5[c * 5 + d];
                accV[0] += w * r[0]; accV[1] += w * r[1];
                accV[2] += w * r[2]; accV[3] += w * r[3];
            }
        }
        // horizontal 5-tap: row i, cols j-2..j+5
        f32x4 c0 = *(const f32x4*)(p + i * 64 + j);
        float col[8];
        col[2] = c0[0]; col[3] = c0[1]; col[4] = c0[2]; col[5] = c0[3];
        col[0] = (j >= 2)     ? p[i * 64 + j - 2] : 0.f;
        col[1] = (j >= 1)     ? p[i * 64 + j - 1] : 0.f;
        col[6] = (j + 4 < 64) ? p[i * 64 + j + 4] : 0.f;
        col[7] = (j + 5 < 64) ? p[i * 64 + j + 5] : 0.f;
        #pragma unroll
        for (int k = 0; k < 4; ++k) {
            #pragma unroll
            for (int d = 0; d < 5; ++d) accH[k] += wh5[c * 5 + d] * col[k + d];
        }
        ushort4 ph, pv_;
        ph.x = f2bf(gelu_exact(accV[0])); ph.y = f2bf(gelu_exact(accV[1]));
        ph.z = f2bf(gelu_exact(accV[2])); ph.w = f2bf(gelu_exact(accV[3]));
        pv_.x = f2bf(gelu_exact(accH[0])); pv_.y = f2bf(gelu_exact(accH[1]));
        pv_.z = f2bf(gelu_exact(accH[2])); pv_.w = f2bf(gelu_exact(accH[3]));
        *(ushort4*)(gh + base) = ph;
        *(ushort4*)(gv + base) = pv_;
        return;
    }
    // ---- QKV + Wo
    __shared__ float xs[64 * 65];
    __shared__ float gl[64];
    int n0 = blockIdx.x * 64;
    int wv_ = t >> 6, lane = t & 63, l16 = lane & 15, quad = lane >> 4;
    stage_bchw4(xp, b, n0, t, xs);
    if (t < 64) {
        float s = 0.f;
        #pragma unroll
        for (int u = 0; u < 8; ++u) s += gap4k[(b * 64 + t) * 8 + u];
        gl[t] = s * (1.f / 4096.f);
    }
    __syncthreads();
    int row = wv_ * 16 + l16;
    int n   = n0 + wv_ * 16 + l16;
    int nb  = n0 + wv_ * 16 + quad * 4;
    bf16x8 ar[2], ag[2];
    #pragma unroll
    for (int ks = 0; ks < 2; ++ks) {
        float vr[8], vg[8];
        #pragma unroll
        for (int j = 0; j < 8; ++j) {
            int k = ks * 32 + quad * 8 + j;
            float xv = xs[k * 65 + row];
            vr[j] = xv; vg[j] = xv * gl[k];
        }
        ar[ks] = cvt8(vr); ag[ks] = cvt8(vg);
    }
    f32x4 acc[4];
    #pragma unroll
    for (int cb = 0; cb < 4; ++cb) acc[cb] = (f32x4){0.f, 0.f, 0.f, 0.f};
    gemm16Tb(ag, Wqb, l16, quad, acc);
    store_bnc_T(qb, b, n, quad, acc, bq, SCALE2);
    #pragma unroll
    for (int cb = 0; cb < 4; ++cb) acc[cb] = (f32x4){0.f, 0.f, 0.f, 0.f};
    gemm16Tb(ag, Wkb, l16, quad, acc);
    store_bnc_T(kb, b, n, quad, acc, bk, 1.f);
    #pragma unroll
    for (int cb = 0; cb < 4; ++cb) acc[cb] = (f32x4){0.f, 0.f, 0.f, 0.f};
    gemm16b(ag, Wvb, l16, quad, acc);
    store_bchw_bf16(vb, b, nb, l16, acc, bv);
    #pragma unroll
    for (int cb = 0; cb < 4; ++cb) acc[cb] = (f32x4){0.f, 0.f, 0.f, 0.f};
    gemm16b(ar, Wob, l16, quad, acc);
    #pragma unroll
    for (int cb = 0; cb < 4; ++cb) {
        int col = cb * 16 + l16;
        float bb = bo[col];
        ushort4 pk;
        float y0 = acc[cb][0] + bb, y1 = acc[cb][1] + bb, y2 = acc[cb][2] + bb, y3 = acc[cb][3] + bb;
        xV[((size_t)(b * Np + nb + 0)) * Cn + col] = y0;
        xV[((size_t)(b * Np + nb + 1)) * Cn + col] = y1;
        xV[((size_t)(b * Np + nb + 2)) * Cn + col] = y2;
        xV[((size_t)(b * Np + nb + 3)) * Cn + col] = y3;
        pk.x = f2bf(y0); pk.y = f2bf(y1); pk.z = f2bf(y2); pk.w = f2bf(y3);
        *(ushort4*)(xVtb + ((size_t)(b * Cn + col)) * Np + nb) = pk;
    }
}

// ---------------------------------------------------------------- attention body (device)
// 256 threads / 64 q-rows / 4 waves share staged 64-kv tiles. NSPLIT=4 splits.
// S^T orientation (register P), PV via 16x16x16, double-buffered global_load_lds.
// Swizzle key(r) = (r ^ (r>>3)) & 7 at 16B-chunk granularity.
// (Round-0 baseline structure: best measured attn dispatch, 44.0 us. DO NOT TOUCH.)
__device__ __forceinline__ void attn_body(
    int xblk, int b, const ushort_t* __restrict__ Qb, const ushort_t* __restrict__ Kb,
    const ushort_t* __restrict__ Vtb, ushort_t* __restrict__ OpB, float* __restrict__ Lpart,
    ushort_t* smem) {
    ushort_t* kt0 = smem;            // [2][4096]
    ushort_t* vt0 = smem + 8192;     // [2][4096]
    int split = xblk >> 6;           // 0..3
    int qt    = xblk & 63;
    int n0    = qt * 64;
    int t     = threadIdx.x;         // 0..255
    int wave  = t >> 6, lane = t & 63;
    int l16   = lane & 15, quad = lane >> 4;

    const ushort_t* qp = Qb + ((size_t)(b * Np) + n0 + wave * 16 + l16) * Cn + quad * 8;
    bf16x8 aq0 = *(const bf16x8*)(qp);
    bf16x8 aq1 = *(const bf16x8*)(qp + 32);

    f32x4 oa[4];
    float psum = 0.f;
    #pragma unroll
    for (int db = 0; db < 4; ++db) oa[db] = (f32x4){0.f, 0.f, 0.f, 0.f};

    int lrow = lane >> 3;
    int kvbase = split * (Np / NSPLIT);      // 1024 kv per split
    const ushort_t* Kg = Qb == nullptr ? nullptr : Kb + ((size_t)b * Np) * Cn;
    const ushort_t* Vg = Vtb + ((size_t)b * Cn) * Np;

    auto stage = [&](int buf, int k0) {
        int wh = wave & 1;
        if (wave < 2) {
            ushort_t* dst = kt0 + buf * 4096 + wh * 2048;
            #pragma unroll
            for (int u = 0; u < 4; ++u) {
                int r = wh * 32 + u * 8 + lrow;
                int jsw = ((lane & 7) ^ lrow ^ (wh * 4 + u)) & 7;
                gload_lds16(Kg + ((size_t)(k0 + r)) * Cn + jsw * 8, dst + u * 512);
            }
        } else {
            ushort_t* dst = vt0 + buf * 4096 + wh * 2048;
            #pragma unroll
            for (int u = 0; u < 4; ++u) {
                int d = wh * 32 + u * 8 + lrow;
                int jsw = ((lane & 7) ^ lrow ^ (wh * 4 + u)) & 7;
                gload_lds16(Vg + (size_t)d * Np + k0 + jsw * 8, dst + u * 512);
            }
        }
    };
    const int NT = (Np / NSPLIT) / 64;       // 16
    stage(0, kvbase);
    __syncthreads();

    for (int m = 0; m < NT; ++m) {
        int cur = m & 1;
        if (m + 1 < NT) stage(1 - cur, kvbase + (m + 1) * 64);
        const ushort_t* ktc = kt0 + cur * 4096;
        const ushort_t* vtc = vt0 + cur * 4096;

        // S^T = K Q : C row = kv_sub, col = query(l16)
        f32x4 sa[4];
        #pragma unroll
        for (int cb = 0; cb < 4; ++cb) sa[cb] = (f32x4){0.f, 0.f, 0.f, 0.f};
        #pragma unroll
        for (int cb = 0; cb < 4; ++cb) {
            int key = ((l16 & 7) ^ (cb * 2 + (l16 >> 3))) & 7;
            const ushort_t* krow = ktc + (cb * 16 + l16) * 64;
            bf16x8 bk0 = *(const bf16x8*)(krow + ((quad    ) ^ key) * 8);
            bf16x8 bk1 = *(const bf16x8*)(krow + ((quad + 4) ^ key) * 8);
            sa[cb] = __builtin_amdgcn_mfma_f32_16x16x32_bf16(bk0, aq0, sa[cb], 0, 0, 0);
            sa[cb] = __builtin_amdgcn_mfma_f32_16x16x32_bf16(bk1, aq1, sa[cb], 0, 0, 0);
        }
        // p = 2^s; truncating bf16 pack straight into PV B-fragments
        bf16x4 pb[4];
        #pragma unroll
        for (int cb = 0; cb < 4; ++cb) {
            float p0 = exp2f(sa[cb][0]), p1 = exp2f(sa[cb][1]);
            float p2 = exp2f(sa[cb][2]), p3 = exp2f(sa[cb][3]);
            psum += (p0 + p1) + (p2 + p3);
            bf16x4 pk;
            pk[0] = (short)f2bf_tr(p0); pk[1] = (short)f2bf_tr(p1);
            pk[2] = (short)f2bf_tr(p2); pk[3] = (short)f2bf_tr(p3);
            pb[cb] = pk;
        }
        // O^T += V^T P^T
        #pragma unroll
        for (int kc = 0; kc < 4; ++kc) {
            #pragma unroll
            for (int db = 0; db < 4; ++db) {
                int d = db * 16 + l16;
                int key = ((l16 & 7) ^ (db * 2 + (l16 >> 3))) & 7;
                int phys = (kc * 2 + (quad >> 1)) ^ key;
                const ushort_t* va = vtc + d * 64 + phys * 8 + (quad & 1) * 4;
                bf16x4 av = *(const bf16x4*)va;
                oa[db] = __builtin_amdgcn_mfma_f32_16x16x16bf16_1k(av, pb[kc], oa[db], 0, 0, 0);
            }
        }
        __syncthreads();
    }
    psum += __shfl_xor(psum, 16, 64);
    psum += __shfl_xor(psum, 32, 64);
    size_t obase = ((size_t)(split * Bn + b)) * Np;
    int n = n0 + wave * 16 + l16;
    if (quad == 0) Lpart[obase + n] = psum;
    #pragma unroll
    for (int db = 0; db < 4; ++db) {
        ushort4 pk;
        pk.x = f2bf(oa[db][0]); pk.y = f2bf(oa[db][1]);
        pk.z = f2bf(oa[db][2]); pk.w = f2bf(oa[db][3]);
        *(ushort4*)(OpB + (obase + n) * Cn + db * 16 + quad * 4) = pk;
    }
}

// hpg body: bf16 gh/gv staged [n][c] stride 72, combined 1x1 (SCALE2 folded, bf16 weights) -> xQb
__device__ __forceinline__ void hpg_body(
    int tile, int b, const ushort_t* __restrict__ gh, const ushort_t* __restrict__ gv,
    const ushort_t* __restrict__ Wc1b, const ushort_t* __restrict__ Wc2b,
    const float* __restrict__ bcv,
    ushort_t* __restrict__ xQb, ushort_t* smem) {
    ushort_t* xs1 = smem;            // 64 x 72
    ushort_t* xs2 = smem + 4608;
    int n0 = tile * 64, t = threadIdx.x;
    int wv_ = t >> 6, lane = t & 63, l16 = lane & 15, quad = lane >> 4;
    #pragma unroll
    for (int u = 0; u < 4; ++u) {
        int lin = u * 256 + t;
        int c = lin >> 4, nl4 = (lin & 15) * 4;
        size_t gi = ((size_t)(b * Cn + c)) * Np + n0 + nl4;
        ushort4 g1 = *(const ushort4*)(gh + gi);
        ushort4 g2 = *(const ushort4*)(gv + gi);
        xs1[(nl4 + 0) * 72 + c] = g1.x; xs1[(nl4 + 1) * 72 + c] = g1.y;
        xs1[(nl4 + 2) * 72 + c] = g1.z; xs1[(nl4 + 3) * 72 + c] = g1.w;
        xs2[(nl4 + 0) * 72 + c] = g2.x; xs2[(nl4 + 1) * 72 + c] = g2.y;
        xs2[(nl4 + 2) * 72 + c] = g2.z; xs2[(nl4 + 3) * 72 + c] = g2.w;
    }
    __syncthreads();
    int row = wv_ * 16 + l16;
    bf16x8 a1[2], a2[2];
    #pragma unroll
    for (int ks = 0; ks < 2; ++ks) {
        a1[ks] = *(const bf16x8*)(xs1 + row * 72 + ks * 32 + quad * 8);
        a2[ks] = *(const bf16x8*)(xs2 + row * 72 + ks * 32 + quad * 8);
    }
    f32x4 acc[4];
    #pragma unroll
    for (int cb = 0; cb < 4; ++cb) acc[cb] = (f32x4){0.f, 0.f, 0.f, 0.f};
    gemm16Tb(a1, Wc1b, l16, quad, acc);
    gemm16Tb(a2, Wc2b, l16, quad, acc);
    store_bnc_T(xQb, b, n0 + wv_ * 16 + l16, quad, acc, bcv, 1.f);
}

// merged launch: x<256 -> attention ; x>=256 -> hpg tile (x-256)
__global__ __launch_bounds__(256) void attn_hpg_kernel(
    const ushort_t* __restrict__ Qb, const ushort_t* __restrict__ Kb,
    const ushort_t* __restrict__ Vtb, ushort_t* __restrict__ OpB, float* __restrict__ Lpart,
    const ushort_t* __restrict__ gh, const ushort_t* __restrict__ gv,
    const ushort_t* __restrict__ Wc1b, const ushort_t* __restrict__ Wc2b,
    const float* __restrict__ bcv, ushort_t* __restrict__ xQb) {
    __shared__ ushort_t smem[16384];   // attn: 2x(4096+4096); hpg: 2x4608
    int b = blockIdx.y;
    if (blockIdx.x < 256)
        attn_body(blockIdx.x, b, Qb, Kb, Vtb, OpB, Lpart, smem);
    else
        hpg_body(blockIdx.x - 256, b, gh, gv, Wc1b, Wc2b, bcv, xQb, smem);
}

// ---------------------------------------------------------------- combine(attn1)+Wl -> xKb
__global__ __launch_bounds__(256) void wl_mfma(
    const ushort_t* __restrict__ OpB, const float* __restrict__ Lp,
    const ushort_t* __restrict__ Wlb, const float* __restrict__ bl, ushort_t* __restrict__ xKb) {
    __shared__ float xs[64 * 65];
    __shared__ float linv[64];
    int b = blockIdx.y, n0 = blockIdx.x * 64, t = threadIdx.x;
    int wv_ = t >> 6, lane = t & 63, l16 = lane & 15, quad = lane >> 4;
    if (t < 64) {
        size_t li = (size_t)b * Np + n0 + t;
        const size_t LS = (size_t)Bn * Np;
        linv[t] = 1.f / (Lp[li] + Lp[LS + li] + Lp[2 * LS + li] + Lp[3 * LS + li]);
    }
    __syncthreads();
    stage_comb(OpB, linv, b, n0, t, xs);
    __syncthreads();
    bf16x8 af[2];
    aload(xs, wv_ * 16 + l16, quad, af);
    f32x4 acc[4];
    #pragma unroll
    for (int cb = 0; cb < 4; ++cb) acc[cb] = (f32x4){0.f, 0.f, 0.f, 0.f};
    gemm16Tb(af, Wlb, l16, quad, acc);
    store_bnc_T(xKb, b, n0 + wv_ * 16 + l16, quad, acc, bl, 1.f);
}

// ---------------------------------------------------------------- combine(attn2)+Wp+res+LayerNorm -> BCHW
__global__ __launch_bounds__(256) void linln_mfma(
    const ushort_t* __restrict__ OpB, const float* __restrict__ Lp,
    const ushort_t* __restrict__ Wpb, const float* __restrict__ bp,
    const float* __restrict__ xV, const float* __restrict__ g, const float* __restrict__ beta,
    float* __restrict__ out) {
    __shared__ float xs[64 * 65];
    __shared__ float linv[64];
    int b = blockIdx.y, n0 = blockIdx.x * 64, t = threadIdx.x;
    int wv_ = t >> 6, lane = t & 63, l16 = lane & 15, quad = lane >> 4;
    if (t < 64) {
        size_t li = (size_t)b * Np + n0 + t;
        const size_t LS = (size_t)Bn * Np;
        linv[t] = 1.f / (Lp[li] + Lp[LS + li] + Lp[2 * LS + li] + Lp[3 * LS + li]);
    }
    __syncthreads();
    stage_comb(OpB, linv, b, n0, t, xs);
    __syncthreads();
    bf16x8 af[2];
    aload(xs, wv_ * 16 + l16, quad, af);
    f32x4 acc[4];
    #pragma unroll
    for (int cb = 0; cb < 4; ++cb) acc[cb] = (f32x4){0.f, 0.f, 0.f, 0.f};
    gemm16b(af, Wpb, l16, quad, acc);
    int nb = n0 + wv_ * 16 + quad * 4;
    float vals[4][4], gc[4], bec[4];
    #pragma unroll
    for (int cb = 0; cb < 4; ++cb) {
        int col = cb * 16 + l16;
        float bb = bp[col];
        gc[cb] = g[col]; bec[cb] = beta[col];
        #pragma unroll
        for (int r = 0; r < 4; ++r)
            vals[cb][r] = acc[cb][r] + bb + xV[((size_t)(b * Np + nb + r)) * Cn + col];
    }
    f32x4 yn[4];
    #pragma unroll
    for (int r = 0; r < 4; ++r) {
        float s = 0.f, s2 = 0.f;
        #pragma unroll
        for (int cb = 0; cb < 4; ++cb) { s += vals[cb][r]; s2 += vals[cb][r] * vals[cb][r]; }
        #pragma unroll
        for (int off = 1; off < 16; off <<= 1) {
            s  += __shfl_xor(s, off, 64);
            s2 += __shfl_xor(s2, off, 64);
        }
        float mu  = s * (1.f / 64.f);
        float var = s2 * (1.f / 64.f) - mu * mu;
        float ivs = rsqrtf(var + 1e-5f);
        #pragma unroll
        for (int cb = 0; cb < 4; ++cb)
            yn[cb][r] = (vals[cb][r] - mu) * ivs * gc[cb] + bec[cb];
    }
    #pragma unroll
    for (int cb = 0; cb < 4; ++cb)
        *(f32x4*)(out + ((size_t)(b * Cn + cb * 16 + l16)) * Np + nb) = yn[cb];
}

// ---------------------------------------------------------------- dw3x3 + GELU (4 outs/thread, float4 loads)
__global__ void dw3x3_gelu_kernel(const float* __restrict__ xin, const float* __restrict__ w,
                                  const float* __restrict__ bias, float* __restrict__ out) {
    int gid = blockIdx.x * 256 + threadIdx.x;      // 262144 threads, 4 outputs each
    int j4 = (gid & 15) * 4;
    int i  = (gid >> 4) & 63;
    int bc = gid >> 10, c = bc & 63;
    const float* p = xin + (size_t)bc * Np;
    float acc[4];
    float bb = bias[c];
    #pragma unroll
    for (int k = 0; k < 4; ++k) acc[k] = bb;
    #pragma unroll
    for (int dy = 0; dy < 3; ++dy) {
        int ii = i + dy - 1;
        if (ii < 0 || ii >= 64) continue;
        const float* pr = p + ii * 64;
        f32x4 mid = *(const f32x4*)(pr + j4);
        float col[6];
        col[1] = mid[0]; col[2] = mid[1]; col[3] = mid[2]; col[4] = mid[3];
        col[0] = (j4 > 0)      ? pr[j4 - 1] : 0.f;
        col[5] = (j4 + 4 < 64) ? pr[j4 + 4] : 0.f;
        #pragma unroll
        for (int dx = 0; dx < 3; ++dx) {
            float wv = w[c * 9 + dy * 3 + dx];
            #pragma unroll
            for (int k = 0; k < 4; ++k) acc[k] += wv * col[k + dx];
        }
    }
    f32x4 o;
    #pragma unroll
    for (int k = 0; k < 4; ++k) o[k] = gelu_exact(acc[k]);
    *(f32x4*)(out + (size_t)bc * Np + i * 64 + j4) = o;
}

// ---------------------------------------------------------------- dsc 1x1 (bf16 weights) + residual -> BCHW
__global__ __launch_bounds__(256) void dsc_mfma(
    const float* __restrict__ X, const ushort_t* __restrict__ Wb, const float* __restrict__ bias,
    const float* __restrict__ res, float* __restrict__ out) {
    __shared__ float xs[64 * 65];
    int b = blockIdx.y, n0 = blockIdx.x * 64, t = threadIdx.x;
    int wv_ = t >> 6, lane = t & 63, l16 = lane & 15, quad = lane >> 4;
    stage_bchw4(X, b, n0, t, xs);
    __syncthreads();
    bf16x8 af[2];
    aload(xs, wv_ * 16 + l16, quad, af);
    f32x4 acc[4];
    #pragma unroll
    for (int cb = 0; cb < 4; ++cb) acc[cb] = (f32x4){0.f, 0.f, 0.f, 0.f};
    gemm16b(af, Wb, l16, quad, acc);
    int nb = n0 + wv_ * 16 + quad * 4;
    #pragma unroll
    for (int cb = 0; cb < 4; ++cb) {
        int col = cb * 16 + l16;
        float bb = bias[col];
        size_t oi = ((size_t)(b * Cn + col)) * Np + nb;
        f32x4 rv = *(const f32x4*)(res + oi);
        f32x4 v4;
        #pragma unroll
        for (int r = 0; r < 4; ++r) v4[r] = acc[cb][r] + bb + rv[r];
        *(f32x4*)(out + oi) = v4;
    }
}

// ---------------------------------------------------------------- bilinear x2 upsample (4 outs/thread)
__global__ void upsample_kernel(const float* __restrict__ in, float* __restrict__ out) {
    int idx = blockIdx.x * 256 + threadIdx.x;     // 1,048,576 threads
    int x4 = (idx & 31) * 4;
    int y  = (idx >> 5) & 127;
    int bc = idx >> 12;
    float sy = y * (63.f / 127.f);
    int y0 = (int)sy;
    float fy = sy - y0;
    int y1 = min(y0 + 1, 63);
    const float* p0 = in + (size_t)bc * Np + y0 * 64;
    const float* p1 = in + (size_t)bc * Np + y1 * 64;
    f32x4 o;
    #pragma unroll
    for (int k = 0; k < 4; ++k) {
        int xo = x4 + k;
        float sx = xo * (63.f / 127.f);
        int x0 = (int)sx;
        float fx = sx - x0;
        int x1 = min(x0 + 1, 63);
        float r0 = p0[x0] + (p0[x1] - p0[x0]) * fx;
        float r1 = p1[x0] + (p1[x1] - p1[x0]) * fx;
        o[k] = r0 + (r1 - r0) * fy;
    }
    *(f32x4*)(out + (size_t)idx * 4) = o;
}

// ----------------------------------------------------------------
extern "C" void kernel_launch(void* const* d_in, const int* in_sizes, int n_in,
                              void* d_out, int out_size, void* d_ws, size_t ws_size,
                              hipStream_t stream) {
    const float* x       = (const float*)d_in[0];
    const float* Wq      = (const float*)d_in[1];
    const float* bq      = (const float*)d_in[2];
    const float* Wk      = (const float*)d_in[3];
    const float* bk      = (const float*)d_in[4];
    const float* Wv      = (const float*)d_in[5];
    const float* bv      = (const float*)d_in[6];
    const float* Wl      = (const float*)d_in[7];
    const float* bl      = (const float*)d_in[8];
    const float* Wo      = (const float*)d_in[9];
    const float* bo      = (const float*)d_in[10];
    const float* Wp      = (const float*)d_in[11];
    const float* bp      = (const float*)d_in[12];
    const float* sch_dw  = (const float*)d_in[13];
    const float* sch_dwb = (const float*)d_in[14];
    const float* sch_pw  = (const float*)d_in[15];
    const float* sch_pwb = (const float*)d_in[16];
    const float* scv_dw  = (const float*)d_in[17];
    const float* scv_dwb = (const float*)d_in[18];
    const float* scv_pw  = (const float*)d_in[19];
    const float* scv_pwb = (const float*)d_in[20];
    const float* convh_w = (const float*)d_in[21];
    const float* convh_b = (const float*)d_in[22];
    const float* dsc_dw  = (const float*)d_in[23];
    const float* dsc_dwb = (const float*)d_in[24];
    const float* dsc_pw  = (const float*)d_in[25];
    const float* dsc_pwb = (const float*)d_in[26];
    const float* ln_g    = (const float*)d_in[27];
    const float* ln_b    = (const float*)d_in[28];

    float* ws = (float*)d_ws;
    const size_t SZ = (size_t)Bn * Np * Cn;   // 1,048,576 elements
    float* xp   = ws;                          // pooled BCHW; later p_norm
    float* xV   = ws + SZ;                     // BNC fp32; later dw3x3 out
    ushort_t* ghb = (ushort_t*)(ws + 2 * SZ);  // bf16 gh/gv (floats 2SZ..3SZ)
    ushort_t* gh  = ghb;
    ushort_t* gv  = ghb + SZ;
    float* f2   = ws + 2 * SZ;                 // dsc out (reuses gh/gv region later)
    ushort_t* bws  = (ushort_t*)(ws + 3 * SZ); // floats 3SZ..6SZ
    ushort_t* qb   = bws;
    ushort_t* kb_  = bws + SZ;
    ushort_t* vb   = bws + 2 * SZ;             // bf16 BCHW (V^T)
    ushort_t* xKb  = bws + 3 * SZ;
    ushort_t* xVtb = bws + 4 * SZ;             // bf16 BCHW (V^T)
    ushort_t* xQb  = bws + 5 * SZ;
    ushort_t* OpB  = (ushort_t*)(ws + 6 * SZ); // bf16 partials, 4 x SZ ushorts (floats 6SZ..8SZ)
    float* gap4k  = ws + 8 * SZ;                        // 2048 (8 partials/image)
    float* Lpart  = gap4k + 4096;                       // NSPLIT*Bn*Np = 65536
    float* wcslot = Lpart + (size_t)NSPLIT * Bn * Np;
    ushort_t* Wc1b = (ushort_t*)wcslot;                 // 4096 ushorts
    ushort_t* Wc2b = Wc1b + 4096;                       // 4096 ushorts (8192 us = 4096 floats)
    float* bcv  = wcslot + 4096;                        // 64 floats
    ushort_t* Wball = (ushort_t*)(bcv + 64);            // 7 x 4096 bf16 weights
    ushort_t* Wqb   = Wball;
    ushort_t* Wkb   = Wball + 4096;
    ushort_t* Wvb   = Wball + 8192;
    ushort_t* Wob   = Wball + 12288;
    ushort_t* Wlb   = Wball + 16384;
    ushort_t* Wpb   = Wball + 20480;
    ushort_t* Wdscb = Wball + 24576;

    dim3 g64(64, Bn);

    // 1) avgpool (vectorized) + GAP partials + weight combine + bf16 weight pre-convert
    avgpool_kernel<<<2048 + 32 + 112, 256, 0, stream>>>(x, xp, gap4k,
                                                  convh_w, convh_b, sch_pw, sch_pwb,
                                                  scv_pw, scv_pwb, Wc1b, Wc2b, bcv,
                                                  Wq, Wk, Wv, Wo, Wl, Wp, dsc_pw, Wball);
    // 2) qkv(+Wo) merged with dwpair (bf16 gh/gv)
    qkv_dw_kernel<<<dim3(64 + 256, Bn), 256, 0, stream>>>(
        xp, gap4k, Wqb, bq, Wkb, bk, Wvb, bv, Wob, bo,
        qb, kb_, vb, xV, xVtb, sch_dw, sch_dwb, scv_dw, scv_dwb, gh, gv);
    // 3) attention 1 merged with hpg (x_Q)
    attn_hpg_kernel<<<dim3(256 + 64, Bn), 256, 0, stream>>>(
        qb, kb_, vb, OpB, Lpart, gh, gv, Wc1b, Wc2b, bcv, xQb);
    // 4) x_K = linear(combine(attn1), Wl)
    wl_mfma<<<g64, 256, 0, stream>>>(OpB, Lpart, Wlb, bl, xKb);
    // 5) attention 2 (same kernel, attn blocks only)
    attn_hpg_kernel<<<dim3(256, Bn), 256, 0, stream>>>(
        xQb, xKb, xVtb, OpB, Lpart, gh, gv, Wc1b, Wc2b, bcv, xQb);
    // 6) prompt = linear(combine, Wp) + x_V ; LN ; -> BCHW (xp reused as p_norm)
    linln_mfma<<<g64, 256, 0, stream>>>(OpB, Lpart, Wpb, bp, xV, ln_g, ln_b, xp);
    // 7) dsc depthwise (xV reused as conv out, vectorized)
    dw3x3_gelu_kernel<<<1024, 256, 0, stream>>>(xp, dsc_dw, dsc_dwb, xV);
    // 8) dsc 1x1 + residual
    dsc_mfma<<<g64, 256, 0, stream>>>(xV, Wdscb, dsc_pwb, xp, f2);
    // 9) bilinear x2
    upsample_kernel<<<4096, 256, 0, stream>>>(f2, (float*)d_out);
}